// Round 1
// baseline (1226.906 us; speedup 1.0000x reference)
//
#include <hip/hip_runtime.h>

#define NP 2048
#define BTOT 8
#define BN_TOT 16384
#define KC 16

// ---------------- squared norms: one wave per row ----------------
__global__ __launch_bounds__(256) void sqnorm_kernel(const float* __restrict__ X,
                                                     int lda, int C,
                                                     float* __restrict__ sq) {
  int wave = threadIdx.x >> 6, lane = threadIdx.x & 63;
  int row = blockIdx.x * 4 + wave;
  float s = 0.f;
  for (int c = lane; c < C; c += 64) {
    float t = X[(size_t)row * lda + c];
    s += t * t;
  }
#pragma unroll
  for (int off = 32; off > 0; off >>= 1) s += __shfl_xor(s, off, 64);
  if (lane == 0) sq[row] = s;
}

// ---------------- pairwise score GEMM: score = 2*dot(xi,xj) - sq_j ----------------
// grid (32, 32, cnt_batches); 64x64 tile, 4x4 micro, 256 threads
__global__ __launch_bounds__(256) void dist_gemm(const float* __restrict__ X, int lda, int K,
                                                 const float* __restrict__ sq,
                                                 float* __restrict__ pd, int batch0) {
  int bz = blockIdx.z;
  const float* Xb = X + (size_t)(batch0 + bz) * NP * lda;
  const float* sqb = sq + (size_t)(batch0 + bz) * NP;
  float* pdb = pd + (size_t)bz * NP * NP;
  int i0 = blockIdx.y * 64, j0 = blockIdx.x * 64;
  __shared__ float At[KC][68];
  __shared__ float Bt[KC][68];
  int t = threadIdx.x;
  int tx = t & 15, ty = t >> 4;
  int lk = t & 15, lr = t >> 4;
  float acc[4][4] = {};
  for (int k0 = 0; k0 < K; k0 += KC) {
    int kk = k0 + lk;
    bool kv = kk < K;
#pragma unroll
    for (int u = 0; u < 4; ++u) {
      int r = lr + u * 16;
      At[lk][r] = kv ? Xb[(size_t)(i0 + r) * lda + kk] : 0.f;
      Bt[lk][r] = kv ? Xb[(size_t)(j0 + r) * lda + kk] : 0.f;
    }
    __syncthreads();
#pragma unroll
    for (int q = 0; q < KC; ++q) {
      float4 a4 = *(const float4*)&At[q][ty * 4];
      float4 b4 = *(const float4*)&Bt[q][tx * 4];
      float a[4] = {a4.x, a4.y, a4.z, a4.w};
      float bv[4] = {b4.x, b4.y, b4.z, b4.w};
#pragma unroll
      for (int ii = 0; ii < 4; ++ii)
#pragma unroll
        for (int jj = 0; jj < 4; ++jj)
          acc[ii][jj] = fmaf(a[ii], bv[jj], acc[ii][jj]);
    }
    __syncthreads();
  }
#pragma unroll
  for (int ii = 0; ii < 4; ++ii) {
    int i = i0 + ty * 4 + ii;
    int j = j0 + tx * 4;
    float4 o;
    o.x = 2.f * acc[ii][0] - sqb[j + 0];
    o.y = 2.f * acc[ii][1] - sqb[j + 1];
    o.z = 2.f * acc[ii][2] - sqb[j + 2];
    o.w = 2.f * acc[ii][3] - sqb[j + 3];
    *(float4*)&pdb[(size_t)i * NP + j] = o;
  }
}

// ---------------- top-16 per row (set semantics, ties -> smaller index) ----------------
// one wave per row, 4 waves/block
__global__ __launch_bounds__(256) void topk_kernel(const float* __restrict__ pd,
                                                   int* __restrict__ idx_out, int batch0) {
  __shared__ float sv[4][1024];
  __shared__ int sj[4][1024];
  int wave = threadIdx.x >> 6, lane = threadIdx.x & 63;
  int row = blockIdx.x * 4 + wave;  // chunk-local row
  const float* prow = pd + (size_t)row * NP;
  float vs[16];
  int js[16];
#pragma unroll
  for (int i = 0; i < 16; ++i) { vs[i] = -__builtin_inff(); js[i] = 1 << 30; }
  for (int tt = 0; tt < NP / 64; ++tt) {
    int j = lane + tt * 64;  // ascending j per lane -> tie keeps smaller j
    float v = prow[j];
    if (v > vs[15]) {
      vs[15] = v; js[15] = j;
#pragma unroll
      for (int p = 15; p > 0; --p) {
        if (vs[p] > vs[p - 1]) {
          float tv = vs[p]; vs[p] = vs[p - 1]; vs[p - 1] = tv;
          int tj = js[p]; js[p] = js[p - 1]; js[p - 1] = tj;
        }
      }
    }
  }
#pragma unroll
  for (int i = 0; i < 16; ++i) {
    sv[wave][lane * 16 + i] = vs[i];
    sj[wave][lane * 16 + i] = js[i];
  }
  __syncthreads();
  int head = 0;
  float hv = sv[wave][lane * 16];
  int hj = sj[wave][lane * 16];
  int grow = batch0 * NP + row;
  int jb = (grow >> 11) << 11;  // global row base of this batch
  for (int r = 0; r < 16; ++r) {
    float mv = hv;
    int mj = hj;
#pragma unroll
    for (int off = 32; off > 0; off >>= 1) {
      float ov = __shfl_xor(mv, off, 64);
      int oj = __shfl_xor(mj, off, 64);
      if (ov > mv || (ov == mv && oj < mj)) { mv = ov; mj = oj; }
    }
    if (lane == 0) idx_out[(size_t)grow * 16 + r] = jb + mj;
    if (hj == mj) {  // j unique -> unique winner
      ++head;
      if (head < 16) {
        hv = sv[wave][lane * 16 + head];
        hj = sj[wave][lane * 16 + head];
      } else {
        hv = -__builtin_inff();
        hj = 1 << 30;
      }
    }
  }
}

// ---------------- point-wise GEMM: Z = X@Wtop (z=0), Y = X@Wbot (z=1) ----------------
// grid (D/64, 256, 2)
__global__ __launch_bounds__(256) void feat_gemm(const float* __restrict__ A, int lda, int K,
                                                 const float* __restrict__ W, int D,
                                                 float* __restrict__ outT,
                                                 float* __restrict__ outB) {
  const float* Wz = W + (size_t)blockIdx.z * K * D;
  float* o = blockIdx.z ? outB : outT;
  int n0 = blockIdx.x * 64, m0 = blockIdx.y * 64;
  __shared__ float At[KC][68];
  __shared__ float Bt[KC][68];
  int t = threadIdx.x;
  int tx = t & 15, ty = t >> 4;
  float acc[4][4] = {};
  for (int k0 = 0; k0 < K; k0 += KC) {
    {
      int lk = t & 15, lr = t >> 4;
      int kk = k0 + lk;
      bool kv = kk < K;
#pragma unroll
      for (int u = 0; u < 4; ++u) {
        int r = lr + u * 16;
        At[lk][r] = kv ? A[(size_t)(m0 + r) * lda + kk] : 0.f;
      }
      int n = t & 63, kq0 = t >> 6;
#pragma unroll
      for (int u = 0; u < 4; ++u) {
        int kq = kq0 + u * 4;
        int kg = k0 + kq;
        Bt[kq][n] = (kg < K) ? Wz[(size_t)kg * D + n0 + n] : 0.f;
      }
    }
    __syncthreads();
#pragma unroll
    for (int q = 0; q < KC; ++q) {
      float4 a4 = *(const float4*)&At[q][ty * 4];
      float4 b4 = *(const float4*)&Bt[q][tx * 4];
      float a[4] = {a4.x, a4.y, a4.z, a4.w};
      float bv[4] = {b4.x, b4.y, b4.z, b4.w};
#pragma unroll
      for (int ii = 0; ii < 4; ++ii)
#pragma unroll
        for (int jj = 0; jj < 4; ++jj)
          acc[ii][jj] = fmaf(a[ii], bv[jj], acc[ii][jj]);
    }
    __syncthreads();
  }
#pragma unroll
  for (int ii = 0; ii < 4; ++ii) {
    float4 o4 = make_float4(acc[ii][0], acc[ii][1], acc[ii][2], acc[ii][3]);
    *(float4*)&o[(size_t)(m0 + ty * 4 + ii) * D + n0 + tx * 4] = o4;
  }
}

// ---------------- gather 16 neighbors, max, BN+ReLU, write into X5 slice ----------------
// grid BN_TOT, block D
__global__ __launch_bounds__(256) void gather_bn_relu(const float* __restrict__ ZT,
                                                      const float* __restrict__ YB,
                                                      const int* __restrict__ idx, int D,
                                                      const float* __restrict__ g,
                                                      const float* __restrict__ bta,
                                                      const float* __restrict__ mu,
                                                      const float* __restrict__ va,
                                                      float* __restrict__ X5, int coff) {
  __shared__ int nb[16];
  int bn = blockIdx.x, d = threadIdx.x;
  if (d < 16) nb[d] = idx[(size_t)bn * 16 + d];
  __syncthreads();
  float mx = -__builtin_inff();
#pragma unroll
  for (int j = 0; j < 16; ++j) mx = fmaxf(mx, YB[(size_t)nb[j] * D + d]);
  float h = ZT[(size_t)bn * D + d] + mx;
  float s = g[d] / sqrtf(va[d] + 1e-3f);
  float val = (h - mu[d]) * s + bta[d];
  X5[(size_t)bn * 512 + coff + d] = fmaxf(val, 0.f);
}

// ---------------- final 512x512 GEMM + BN + ReLU ----------------
// grid (8, 256)
__global__ __launch_bounds__(256) void final_gemm(const float* __restrict__ A,
                                                  const float* __restrict__ W,
                                                  const float* __restrict__ g,
                                                  const float* __restrict__ bta,
                                                  const float* __restrict__ mu,
                                                  const float* __restrict__ va,
                                                  float* __restrict__ out) {
  const int K = 512, D = 512;
  int n0 = blockIdx.x * 64, m0 = blockIdx.y * 64;
  __shared__ float At[KC][68];
  __shared__ float Bt[KC][68];
  int t = threadIdx.x;
  int tx = t & 15, ty = t >> 4;
  float acc[4][4] = {};
  for (int k0 = 0; k0 < K; k0 += KC) {
    {
      int lk = t & 15, lr = t >> 4;
      int kk = k0 + lk;
#pragma unroll
      for (int u = 0; u < 4; ++u) {
        int r = lr + u * 16;
        At[lk][r] = A[(size_t)(m0 + r) * 512 + kk];
      }
      int n = t & 63, kq0 = t >> 6;
#pragma unroll
      for (int u = 0; u < 4; ++u) {
        int kq = kq0 + u * 4;
        Bt[kq][n] = W[(size_t)(k0 + kq) * D + n0 + n];
      }
    }
    __syncthreads();
#pragma unroll
    for (int q = 0; q < KC; ++q) {
      float4 a4 = *(const float4*)&At[q][ty * 4];
      float4 b4 = *(const float4*)&Bt[q][tx * 4];
      float a[4] = {a4.x, a4.y, a4.z, a4.w};
      float bv[4] = {b4.x, b4.y, b4.z, b4.w};
#pragma unroll
      for (int ii = 0; ii < 4; ++ii)
#pragma unroll
        for (int jj = 0; jj < 4; ++jj)
          acc[ii][jj] = fmaf(a[ii], bv[jj], acc[ii][jj]);
    }
    __syncthreads();
  }
  float sc[4], tc[4];
#pragma unroll
  for (int jj = 0; jj < 4; ++jj) {
    int col = n0 + tx * 4 + jj;
    float s = g[col] / sqrtf(va[col] + 1e-3f);
    sc[jj] = s;
    tc[jj] = bta[col] - mu[col] * s;
  }
#pragma unroll
  for (int ii = 0; ii < 4; ++ii) {
    float4 o4;
    o4.x = fmaxf(acc[ii][0] * sc[0] + tc[0], 0.f);
    o4.y = fmaxf(acc[ii][1] * sc[1] + tc[1], 0.f);
    o4.z = fmaxf(acc[ii][2] * sc[2] + tc[2], 0.f);
    o4.w = fmaxf(acc[ii][3] * sc[3] + tc[3], 0.f);
    *(float4*)&out[(size_t)(m0 + ty * 4 + ii) * 512 + n0 + tx * 4] = o4;
  }
}

extern "C" void kernel_launch(void* const* d_in, const int* in_sizes, int n_in,
                              void* d_out, int out_size, void* d_ws, size_t ws_size,
                              hipStream_t stream) {
  const float* x = (const float*)d_in[0];
  const float *W[5], *g[5], *bt[5], *mu[5], *va[5];
  for (int j = 0; j < 5; ++j) {
    W[j] = (const float*)d_in[1 + j * 5 + 0];
    g[j] = (const float*)d_in[1 + j * 5 + 1];
    bt[j] = (const float*)d_in[1 + j * 5 + 2];
    mu[j] = (const float*)d_in[1 + j * 5 + 3];
    va[j] = (const float*)d_in[1 + j * 5 + 4];
  }
  char* p = (char*)d_ws;
  float* X5 = (float*)p; p += (size_t)BN_TOT * 512 * 4;   // concat [x1|x2|x3|x4]
  float* ZT = (float*)p; p += (size_t)BN_TOT * 256 * 4;   // X @ Wtop
  float* YB = (float*)p; p += (size_t)BN_TOT * 256 * 4;   // X @ Wbot
  int* idx = (int*)p;    p += (size_t)BN_TOT * 16 * 4;    // global neighbor rows
  float* sq = (float*)p; p += (size_t)BN_TOT * 4;
  float* pd = (float*)p;
  size_t used = (size_t)(p - (char*)d_ws);
  size_t pdcap = (ws_size > used) ? (ws_size - used) / ((size_t)NP * NP * 4) : 0;
  int nb = (int)(pdcap < 1 ? 1 : (pdcap > (size_t)BTOT ? (size_t)BTOT : pdcap));

  struct Blk { const float* A; int lda, C, D, coff, w; };
  Blk blks[4] = {
      {x, 3, 3, 64, 0, 0},
      {X5 + 0, 512, 64, 64, 64, 1},
      {X5 + 64, 512, 64, 128, 128, 2},
      {X5 + 128, 512, 128, 256, 256, 3},
  };
  for (int q = 0; q < 4; ++q) {
    Blk& B = blks[q];
    sqnorm_kernel<<<BN_TOT / 4, 256, 0, stream>>>(B.A, B.lda, B.C, sq);
    for (int b0 = 0; b0 < BTOT; b0 += nb) {
      int cnt = (BTOT - b0 < nb) ? (BTOT - b0) : nb;
      dist_gemm<<<dim3(32, 32, cnt), 256, 0, stream>>>(B.A, B.lda, B.C, sq, pd, b0);
      topk_kernel<<<cnt * NP / 4, 256, 0, stream>>>(pd, idx, b0);
    }
    feat_gemm<<<dim3(B.D / 64, BN_TOT / 64, 2), 256, 0, stream>>>(
        B.A, B.lda, B.C, W[B.w], B.D, ZT, YB);
    gather_bn_relu<<<BN_TOT, B.D, 0, stream>>>(ZT, YB, idx, B.D, g[B.w], bt[B.w], mu[B.w],
                                               va[B.w], X5, B.coff);
  }
  final_gemm<<<dim3(512 / 64, BN_TOT / 64), 256, 0, stream>>>(X5, W[4], g[4], bt[4], mu[4],
                                                              va[4], (float*)d_out);
}

// Round 2
// 929.354 us; speedup vs baseline: 1.3202x; 1.3202x over previous
//
#include <hip/hip_runtime.h>

#define NP 2048
#define BTOT 8
#define BN_TOT 16384
#define KC 16

// ---------------- squared norms: one wave per row ----------------
__global__ __launch_bounds__(256) void sqnorm_kernel(const float* __restrict__ X,
                                                     int lda, int C,
                                                     float* __restrict__ sq) {
  int wave = threadIdx.x >> 6, lane = threadIdx.x & 63;
  int row = blockIdx.x * 4 + wave;
  float s = 0.f;
  for (int c = lane; c < C; c += 64) {
    float t = X[(size_t)row * lda + c];
    s += t * t;
  }
#pragma unroll
  for (int off = 32; off > 0; off >>= 1) s += __shfl_xor(s, off, 64);
  if (lane == 0) sq[row] = s;
}

// ---------------- pairwise score GEMM: score = 2*dot(xi,xj) - sq_j ----------------
// grid (32, 32, cnt_batches); 64x64 tile, 4x4 micro, 256 threads
__global__ __launch_bounds__(256) void dist_gemm(const float* __restrict__ X, int lda, int K,
                                                 const float* __restrict__ sq,
                                                 float* __restrict__ pd, int batch0) {
  int bz = blockIdx.z;
  const float* Xb = X + (size_t)(batch0 + bz) * NP * lda;
  const float* sqb = sq + (size_t)(batch0 + bz) * NP;
  float* pdb = pd + (size_t)bz * NP * NP;
  int i0 = blockIdx.y * 64, j0 = blockIdx.x * 64;
  __shared__ float At[KC][68];
  __shared__ float Bt[KC][68];
  int t = threadIdx.x;
  int tx = t & 15, ty = t >> 4;
  int lk = t & 15, lr = t >> 4;
  float acc[4][4] = {};
  for (int k0 = 0; k0 < K; k0 += KC) {
    int kk = k0 + lk;
    bool kv = kk < K;
#pragma unroll
    for (int u = 0; u < 4; ++u) {
      int r = lr + u * 16;
      At[lk][r] = kv ? Xb[(size_t)(i0 + r) * lda + kk] : 0.f;
      Bt[lk][r] = kv ? Xb[(size_t)(j0 + r) * lda + kk] : 0.f;
    }
    __syncthreads();
#pragma unroll
    for (int q = 0; q < KC; ++q) {
      float4 a4 = *(const float4*)&At[q][ty * 4];
      float4 b4 = *(const float4*)&Bt[q][tx * 4];
      float a[4] = {a4.x, a4.y, a4.z, a4.w};
      float bv[4] = {b4.x, b4.y, b4.z, b4.w};
#pragma unroll
      for (int ii = 0; ii < 4; ++ii)
#pragma unroll
        for (int jj = 0; jj < 4; ++jj)
          acc[ii][jj] = fmaf(a[ii], bv[jj], acc[ii][jj]);
    }
    __syncthreads();
  }
#pragma unroll
  for (int ii = 0; ii < 4; ++ii) {
    int i = i0 + ty * 4 + ii;
    int j = j0 + tx * 4;
    float4 o;
    o.x = 2.f * acc[ii][0] - sqb[j + 0];
    o.y = 2.f * acc[ii][1] - sqb[j + 1];
    o.z = 2.f * acc[ii][2] - sqb[j + 2];
    o.w = 2.f * acc[ii][3] - sqb[j + 3];
    *(float4*)&pdb[(size_t)i * NP + j] = o;
  }
}

// ---------------- top-16 per row: threshold prefilter + wave select ----------------
// One wave per row, 4 waves/block. Output is the exact top-16 SET (ties at the
// 16th value resolved by smallest index, matching lax.top_k's selection set);
// order within the 16 is irrelevant downstream (max-pool).
__global__ __launch_bounds__(256) void topk_kernel(const float* __restrict__ pd,
                                                   int* __restrict__ idx_out, int batch0) {
  __shared__ float sv[4][1024];
  __shared__ int sj[4][1024];
  int wave = threadIdx.x >> 6, lane = threadIdx.x & 63;
  int row = blockIdx.x * 4 + wave;  // chunk-local row
  const float* prow = pd + (size_t)row * NP;
  int grow = batch0 * NP + row;
  int jb = (grow >> 11) << 11;  // global row base of this batch
  int* out = idx_out + (size_t)grow * 16;

  // 1) load 32 values per lane (coalesced), track lane max
  float v[32];
#pragma unroll
  for (int t = 0; t < 32; ++t) v[t] = prow[lane + t * 64];
  float lmax = v[0];
#pragma unroll
  for (int t = 1; t < 32; ++t) lmax = fmaxf(lmax, v[t]);

  // 2) T0 = 16th-largest lane max (exact rank; ranks are a permutation 0..63)
  int rank = 0;
#pragma unroll
  for (int s = 0; s < 64; ++s) {
    float o = __shfl(lmax, s, 64);
    rank += (o > lmax) || (o == lmax && s < lane);
  }
  unsigned long long m15 = __ballot(rank == 15);
  float T0 = __shfl(lmax, (int)__builtin_ctzll(m15), 64);
  // >=16 values satisfy v >= T0 (16 lanes have lmax >= T0), and every member of
  // the true top-16 is >= the true 16th-largest >= T0 -> filter is lossless.

  // 3) ballot-compact survivors to LDS in ascending-j order
  unsigned long long lowmask = (1ull << lane) - 1ull;
  int base = 0;
#pragma unroll
  for (int t = 0; t < 32; ++t) {
    bool keep = (v[t] >= T0);
    unsigned long long mk = __ballot(keep);
    if (keep) {
      int pos = base + (int)__popcll(mk & lowmask);
      if (pos < 1024) { sv[wave][pos] = v[t]; sj[wave][pos] = lane + t * 64; }
    }
    base += (int)__popcll(mk);
  }
  int cnt = base;

  if (cnt <= 1024) {
    __threadfence_block();  // make cross-lane LDS writes visible within the wave
    // 4) 16 rounds of wave argmax (value desc, index asc)
    for (int r = 0; r < 16; ++r) {
      float lbv = -__builtin_inff();
      int lbj = 1 << 30, lbp = -1;
      for (int i = lane; i < cnt; i += 64) {
        float cv = sv[wave][i];
        int cj = sj[wave][i];
        if (cv > lbv || (cv == lbv && cj < lbj)) { lbv = cv; lbj = cj; lbp = i; }
      }
      float bv = lbv;
      int bj = lbj;
#pragma unroll
      for (int off = 32; off > 0; off >>= 1) {
        float ov = __shfl_xor(bv, off, 64);
        int oj = __shfl_xor(bj, off, 64);
        if (ov > bv || (ov == bv && oj < bj)) { bv = ov; bj = oj; }
      }
      if (lane == 0) out[r] = jb + bj;
      if (lbp >= 0 && lbj == bj) sv[wave][lbp] = -__builtin_inff();  // j unique -> one owner
      __threadfence_block();
    }
    return;
  }

  // ---- fallback (pathological ties; never expected): per-lane insertion + head merge ----
  {
    float vs[16];
    int js[16];
#pragma unroll
    for (int i = 0; i < 16; ++i) { vs[i] = -__builtin_inff(); js[i] = 1 << 30; }
    for (int t = 0; t < 32; ++t) {
      int j = lane + t * 64;
      float val = v[t];
      if (val > vs[15]) {
        vs[15] = val; js[15] = j;
#pragma unroll
        for (int p = 15; p > 0; --p) {
          if (vs[p] > vs[p - 1]) {
            float tv = vs[p]; vs[p] = vs[p - 1]; vs[p - 1] = tv;
            int tj = js[p]; js[p] = js[p - 1]; js[p - 1] = tj;
          }
        }
      }
    }
#pragma unroll
    for (int i = 0; i < 16; ++i) {
      sv[wave][lane * 16 + i] = vs[i];  // own slots only; no cross-lane reads
      sj[wave][lane * 16 + i] = js[i];
    }
    int head = 0;
    float hv = sv[wave][lane * 16];
    int hj = sj[wave][lane * 16];
    for (int r = 0; r < 16; ++r) {
      float mv = hv;
      int mj = hj;
#pragma unroll
      for (int off = 32; off > 0; off >>= 1) {
        float ov = __shfl_xor(mv, off, 64);
        int oj = __shfl_xor(mj, off, 64);
        if (ov > mv || (ov == mv && oj < mj)) { mv = ov; mj = oj; }
      }
      if (lane == 0) out[r] = jb + mj;
      if (hj == mj) {
        ++head;
        if (head < 16) {
          hv = sv[wave][lane * 16 + head];
          hj = sj[wave][lane * 16 + head];
        } else {
          hv = -__builtin_inff();
          hj = 1 << 30;
        }
      }
    }
  }
}

// ---------------- point-wise GEMM: Z = X@Wtop (z=0), Y = X@Wbot (z=1) ----------------
// grid (D/64, 256, 2)
__global__ __launch_bounds__(256) void feat_gemm(const float* __restrict__ A, int lda, int K,
                                                 const float* __restrict__ W, int D,
                                                 float* __restrict__ outT,
                                                 float* __restrict__ outB) {
  const float* Wz = W + (size_t)blockIdx.z * K * D;
  float* o = blockIdx.z ? outB : outT;
  int n0 = blockIdx.x * 64, m0 = blockIdx.y * 64;
  __shared__ float At[KC][68];
  __shared__ float Bt[KC][68];
  int t = threadIdx.x;
  int tx = t & 15, ty = t >> 4;
  float acc[4][4] = {};
  for (int k0 = 0; k0 < K; k0 += KC) {
    {
      int lk = t & 15, lr = t >> 4;
      int kk = k0 + lk;
      bool kv = kk < K;
#pragma unroll
      for (int u = 0; u < 4; ++u) {
        int r = lr + u * 16;
        At[lk][r] = kv ? A[(size_t)(m0 + r) * lda + kk] : 0.f;
      }
      int n = t & 63, kq0 = t >> 6;
#pragma unroll
      for (int u = 0; u < 4; ++u) {
        int kq = kq0 + u * 4;
        int kg = k0 + kq;
        Bt[kq][n] = (kg < K) ? Wz[(size_t)kg * D + n0 + n] : 0.f;
      }
    }
    __syncthreads();
#pragma unroll
    for (int q = 0; q < KC; ++q) {
      float4 a4 = *(const float4*)&At[q][ty * 4];
      float4 b4 = *(const float4*)&Bt[q][tx * 4];
      float a[4] = {a4.x, a4.y, a4.z, a4.w};
      float bv[4] = {b4.x, b4.y, b4.z, b4.w};
#pragma unroll
      for (int ii = 0; ii < 4; ++ii)
#pragma unroll
        for (int jj = 0; jj < 4; ++jj)
          acc[ii][jj] = fmaf(a[ii], bv[jj], acc[ii][jj]);
    }
    __syncthreads();
  }
#pragma unroll
  for (int ii = 0; ii < 4; ++ii) {
    float4 o4 = make_float4(acc[ii][0], acc[ii][1], acc[ii][2], acc[ii][3]);
    *(float4*)&o[(size_t)(m0 + ty * 4 + ii) * D + n0 + tx * 4] = o4;
  }
}

// ---------------- gather 16 neighbors, max, BN+ReLU, write into X5 slice ----------------
// grid BN_TOT, block D
__global__ __launch_bounds__(256) void gather_bn_relu(const float* __restrict__ ZT,
                                                      const float* __restrict__ YB,
                                                      const int* __restrict__ idx, int D,
                                                      const float* __restrict__ g,
                                                      const float* __restrict__ bta,
                                                      const float* __restrict__ mu,
                                                      const float* __restrict__ va,
                                                      float* __restrict__ X5, int coff) {
  __shared__ int nb[16];
  int bn = blockIdx.x, d = threadIdx.x;
  if (d < 16) nb[d] = idx[(size_t)bn * 16 + d];
  __syncthreads();
  float mx = -__builtin_inff();
#pragma unroll
  for (int j = 0; j < 16; ++j) mx = fmaxf(mx, YB[(size_t)nb[j] * D + d]);
  float h = ZT[(size_t)bn * D + d] + mx;
  float s = g[d] / sqrtf(va[d] + 1e-3f);
  float val = (h - mu[d]) * s + bta[d];
  X5[(size_t)bn * 512 + coff + d] = fmaxf(val, 0.f);
}

// ---------------- final 512x512 GEMM + BN + ReLU ----------------
// grid (8, 256)
__global__ __launch_bounds__(256) void final_gemm(const float* __restrict__ A,
                                                  const float* __restrict__ W,
                                                  const float* __restrict__ g,
                                                  const float* __restrict__ bta,
                                                  const float* __restrict__ mu,
                                                  const float* __restrict__ va,
                                                  float* __restrict__ out) {
  const int K = 512, D = 512;
  int n0 = blockIdx.x * 64, m0 = blockIdx.y * 64;
  __shared__ float At[KC][68];
  __shared__ float Bt[KC][68];
  int t = threadIdx.x;
  int tx = t & 15, ty = t >> 4;
  float acc[4][4] = {};
  for (int k0 = 0; k0 < K; k0 += KC) {
    {
      int lk = t & 15, lr = t >> 4;
      int kk = k0 + lk;
#pragma unroll
      for (int u = 0; u < 4; ++u) {
        int r = lr + u * 16;
        At[lk][r] = A[(size_t)(m0 + r) * 512 + kk];
      }
      int n = t & 63, kq0 = t >> 6;
#pragma unroll
      for (int u = 0; u < 4; ++u) {
        int kq = kq0 + u * 4;
        Bt[kq][n] = W[(size_t)(k0 + kq) * D + n0 + n];
      }
    }
    __syncthreads();
#pragma unroll
    for (int q = 0; q < KC; ++q) {
      float4 a4 = *(const float4*)&At[q][ty * 4];
      float4 b4 = *(const float4*)&Bt[q][tx * 4];
      float a[4] = {a4.x, a4.y, a4.z, a4.w};
      float bv[4] = {b4.x, b4.y, b4.z, b4.w};
#pragma unroll
      for (int ii = 0; ii < 4; ++ii)
#pragma unroll
        for (int jj = 0; jj < 4; ++jj)
          acc[ii][jj] = fmaf(a[ii], bv[jj], acc[ii][jj]);
    }
    __syncthreads();
  }
  float sc[4], tc[4];
#pragma unroll
  for (int jj = 0; jj < 4; ++jj) {
    int col = n0 + tx * 4 + jj;
    float s = g[col] / sqrtf(va[col] + 1e-3f);
    sc[jj] = s;
    tc[jj] = bta[col] - mu[col] * s;
  }
#pragma unroll
  for (int ii = 0; ii < 4; ++ii) {
    float4 o4;
    o4.x = fmaxf(acc[ii][0] * sc[0] + tc[0], 0.f);
    o4.y = fmaxf(acc[ii][1] * sc[1] + tc[1], 0.f);
    o4.z = fmaxf(acc[ii][2] * sc[2] + tc[2], 0.f);
    o4.w = fmaxf(acc[ii][3] * sc[3] + tc[3], 0.f);
    *(float4*)&out[(size_t)(m0 + ty * 4 + ii) * 512 + n0 + tx * 4] = o4;
  }
}

extern "C" void kernel_launch(void* const* d_in, const int* in_sizes, int n_in,
                              void* d_out, int out_size, void* d_ws, size_t ws_size,
                              hipStream_t stream) {
  const float* x = (const float*)d_in[0];
  const float *W[5], *g[5], *bt[5], *mu[5], *va[5];
  for (int j = 0; j < 5; ++j) {
    W[j] = (const float*)d_in[1 + j * 5 + 0];
    g[j] = (const float*)d_in[1 + j * 5 + 1];
    bt[j] = (const float*)d_in[1 + j * 5 + 2];
    mu[j] = (const float*)d_in[1 + j * 5 + 3];
    va[j] = (const float*)d_in[1 + j * 5 + 4];
  }
  char* p = (char*)d_ws;
  float* X5 = (float*)p; p += (size_t)BN_TOT * 512 * 4;   // concat [x1|x2|x3|x4]
  float* ZT = (float*)p; p += (size_t)BN_TOT * 256 * 4;   // X @ Wtop
  float* YB = (float*)p; p += (size_t)BN_TOT * 256 * 4;   // X @ Wbot
  int* idx = (int*)p;    p += (size_t)BN_TOT * 16 * 4;    // global neighbor rows
  float* sq = (float*)p; p += (size_t)BN_TOT * 4;
  float* pd = (float*)p;
  size_t used = (size_t)(p - (char*)d_ws);
  size_t pdcap = (ws_size > used) ? (ws_size - used) / ((size_t)NP * NP * 4) : 0;
  int nb = (int)(pdcap < 1 ? 1 : (pdcap > (size_t)BTOT ? (size_t)BTOT : pdcap));

  struct Blk { const float* A; int lda, C, D, coff, w; };
  Blk blks[4] = {
      {x, 3, 3, 64, 0, 0},
      {X5 + 0, 512, 64, 64, 64, 1},
      {X5 + 64, 512, 64, 128, 128, 2},
      {X5 + 128, 512, 128, 256, 256, 3},
  };
  for (int q = 0; q < 4; ++q) {
    Blk& B = blks[q];
    sqnorm_kernel<<<BN_TOT / 4, 256, 0, stream>>>(B.A, B.lda, B.C, sq);
    for (int b0 = 0; b0 < BTOT; b0 += nb) {
      int cnt = (BTOT - b0 < nb) ? (BTOT - b0) : nb;
      dist_gemm<<<dim3(32, 32, cnt), 256, 0, stream>>>(B.A, B.lda, B.C, sq, pd, b0);
      topk_kernel<<<cnt * NP / 4, 256, 0, stream>>>(pd, idx, b0);
    }
    feat_gemm<<<dim3(B.D / 64, BN_TOT / 64, 2), 256, 0, stream>>>(
        B.A, B.lda, B.C, W[B.w], B.D, ZT, YB);
    gather_bn_relu<<<BN_TOT, B.D, 0, stream>>>(ZT, YB, idx, B.D, g[B.w], bt[B.w], mu[B.w],
                                               va[B.w], X5, B.coff);
  }
  final_gemm<<<dim3(512 / 64, BN_TOT / 64), 256, 0, stream>>>(X5, W[4], g[4], bt[4], mu[4],
                                                              va[4], (float*)d_out);
}

// Round 3
// 928.195 us; speedup vs baseline: 1.3218x; 1.0012x over previous
//
#include <hip/hip_runtime.h>

#define NP 2048
#define BTOT 8
#define BN_TOT 16384
#define KC 16

// ---------------- squared norms: one wave per row ----------------
__global__ __launch_bounds__(256) void sqnorm_kernel(const float* __restrict__ X,
                                                     int lda, int C,
                                                     float* __restrict__ sq) {
  int wave = threadIdx.x >> 6, lane = threadIdx.x & 63;
  int row = blockIdx.x * 4 + wave;
  float s = 0.f;
  for (int c = lane; c < C; c += 64) {
    float t = X[(size_t)row * lda + c];
    s += t * t;
  }
#pragma unroll
  for (int off = 32; off > 0; off >>= 1) s += __shfl_xor(s, off, 64);
  if (lane == 0) sq[row] = s;
}

// ---------------- pairwise score GEMM: score = 2*dot(xi,xj) - sq_j ----------------
// 128x128 tile, 8x8 micro (2x2 grid of 4x4 over 64-halves), 256 threads.
// grid (16, 16, cnt_batches)
__global__ __launch_bounds__(256) void dist_gemm(const float* __restrict__ X, int lda, int K,
                                                 const float* __restrict__ sq,
                                                 float* __restrict__ pd, int batch0) {
  int bz = blockIdx.z;
  const float* Xb = X + (size_t)(batch0 + bz) * NP * lda;
  const float* sqb = sq + (size_t)(batch0 + bz) * NP;
  float* pdb = pd + (size_t)bz * NP * NP;
  int i0 = blockIdx.y * 128, j0 = blockIdx.x * 128;
  __shared__ float At[KC][132];
  __shared__ float Bt[KC][132];
  int t = threadIdx.x;
  int tx = t & 15, ty = t >> 4;
  int lk = t & 15, lr = t >> 4;
  float acc[2][2][4][4] = {};
  for (int k0 = 0; k0 < K; k0 += KC) {
    int kk = k0 + lk;
    bool kv = kk < K;
#pragma unroll
    for (int u = 0; u < 8; ++u) {
      int r = lr + u * 16;
      At[lk][r] = kv ? Xb[(size_t)(i0 + r) * lda + kk] : 0.f;
      Bt[lk][r] = kv ? Xb[(size_t)(j0 + r) * lda + kk] : 0.f;
    }
    __syncthreads();
#pragma unroll
    for (int q = 0; q < KC; ++q) {
      float4 a0 = *(const float4*)&At[q][ty * 4];
      float4 a1 = *(const float4*)&At[q][64 + ty * 4];
      float4 b0 = *(const float4*)&Bt[q][tx * 4];
      float4 b1 = *(const float4*)&Bt[q][64 + tx * 4];
      float a[2][4] = {{a0.x, a0.y, a0.z, a0.w}, {a1.x, a1.y, a1.z, a1.w}};
      float b[2][4] = {{b0.x, b0.y, b0.z, b0.w}, {b1.x, b1.y, b1.z, b1.w}};
#pragma unroll
      for (int hi = 0; hi < 2; ++hi)
#pragma unroll
        for (int hj = 0; hj < 2; ++hj)
#pragma unroll
          for (int ii = 0; ii < 4; ++ii)
#pragma unroll
            for (int jj = 0; jj < 4; ++jj)
              acc[hi][hj][ii][jj] = fmaf(a[hi][ii], b[hj][jj], acc[hi][hj][ii][jj]);
    }
    __syncthreads();
  }
  float4 sqv[2];
  sqv[0] = *(const float4*)&sqb[j0 + tx * 4];
  sqv[1] = *(const float4*)&sqb[j0 + 64 + tx * 4];
#pragma unroll
  for (int hi = 0; hi < 2; ++hi)
#pragma unroll
    for (int ii = 0; ii < 4; ++ii) {
      int i = i0 + hi * 64 + ty * 4 + ii;
#pragma unroll
      for (int hj = 0; hj < 2; ++hj) {
        int j = j0 + hj * 64 + tx * 4;
        float4 o;
        o.x = 2.f * acc[hi][hj][ii][0] - sqv[hj].x;
        o.y = 2.f * acc[hi][hj][ii][1] - sqv[hj].y;
        o.z = 2.f * acc[hi][hj][ii][2] - sqv[hj].z;
        o.w = 2.f * acc[hi][hj][ii][3] - sqv[hj].w;
        *(float4*)&pdb[(size_t)i * NP + j] = o;
      }
    }
}

// ---------------- top-16 per row: threshold prefilter + wave select ----------------
__global__ __launch_bounds__(256) void topk_kernel(const float* __restrict__ pd,
                                                   int* __restrict__ idx_out, int batch0) {
  __shared__ float sv[4][1024];
  __shared__ int sj[4][1024];
  int wave = threadIdx.x >> 6, lane = threadIdx.x & 63;
  int row = blockIdx.x * 4 + wave;  // chunk-local row
  const float* prow = pd + (size_t)row * NP;
  int grow = batch0 * NP + row;
  int jb = (grow >> 11) << 11;  // global row base of this batch
  int* out = idx_out + (size_t)grow * 16;

  // 1) load 32 values per lane (coalesced), track lane max
  float v[32];
#pragma unroll
  for (int t = 0; t < 32; ++t) v[t] = prow[lane + t * 64];
  float lmax = v[0];
#pragma unroll
  for (int t = 1; t < 32; ++t) lmax = fmaxf(lmax, v[t]);

  // 2) T0 = 16th-largest lane max (exact rank)
  int rank = 0;
#pragma unroll
  for (int s = 0; s < 64; ++s) {
    float o = __shfl(lmax, s, 64);
    rank += (o > lmax) || (o == lmax && s < lane);
  }
  unsigned long long m15 = __ballot(rank == 15);
  float T0 = __shfl(lmax, (int)__builtin_ctzll(m15), 64);

  // 3) ballot-compact survivors to LDS in ascending-j order
  unsigned long long lowmask = (1ull << lane) - 1ull;
  int base = 0;
#pragma unroll
  for (int t = 0; t < 32; ++t) {
    bool keep = (v[t] >= T0);
    unsigned long long mk = __ballot(keep);
    if (keep) {
      int pos = base + (int)__popcll(mk & lowmask);
      if (pos < 1024) { sv[wave][pos] = v[t]; sj[wave][pos] = lane + t * 64; }
    }
    base += (int)__popcll(mk);
  }
  int cnt = base;

  if (cnt <= 1024) {
    __threadfence_block();
    for (int r = 0; r < 16; ++r) {
      float lbv = -__builtin_inff();
      int lbj = 1 << 30, lbp = -1;
      for (int i = lane; i < cnt; i += 64) {
        float cv = sv[wave][i];
        int cj = sj[wave][i];
        if (cv > lbv || (cv == lbv && cj < lbj)) { lbv = cv; lbj = cj; lbp = i; }
      }
      float bv = lbv;
      int bj = lbj;
#pragma unroll
      for (int off = 32; off > 0; off >>= 1) {
        float ov = __shfl_xor(bv, off, 64);
        int oj = __shfl_xor(bj, off, 64);
        if (ov > bv || (ov == bv && oj < bj)) { bv = ov; bj = oj; }
      }
      if (lane == 0) out[r] = jb + bj;
      if (lbp >= 0 && lbj == bj) sv[wave][lbp] = -__builtin_inff();
      __threadfence_block();
    }
    return;
  }

  // ---- fallback (pathological ties; never expected) ----
  {
    float vs[16];
    int js[16];
#pragma unroll
    for (int i = 0; i < 16; ++i) { vs[i] = -__builtin_inff(); js[i] = 1 << 30; }
    for (int t = 0; t < 32; ++t) {
      int j = lane + t * 64;
      float val = v[t];
      if (val > vs[15]) {
        vs[15] = val; js[15] = j;
#pragma unroll
        for (int p = 15; p > 0; --p) {
          if (vs[p] > vs[p - 1]) {
            float tv = vs[p]; vs[p] = vs[p - 1]; vs[p - 1] = tv;
            int tj = js[p]; js[p] = js[p - 1]; js[p - 1] = tj;
          }
        }
      }
    }
#pragma unroll
    for (int i = 0; i < 16; ++i) {
      sv[wave][lane * 16 + i] = vs[i];
      sj[wave][lane * 16 + i] = js[i];
    }
    int head = 0;
    float hv = sv[wave][lane * 16];
    int hj = sj[wave][lane * 16];
    for (int r = 0; r < 16; ++r) {
      float mv = hv;
      int mj = hj;
#pragma unroll
      for (int off = 32; off > 0; off >>= 1) {
        float ov = __shfl_xor(mv, off, 64);
        int oj = __shfl_xor(mj, off, 64);
        if (ov > mv || (ov == mv && oj < mj)) { mv = ov; mj = oj; }
      }
      if (lane == 0) out[r] = jb + mj;
      if (hj == mj) {
        ++head;
        if (head < 16) {
          hv = sv[wave][lane * 16 + head];
          hj = sj[wave][lane * 16 + head];
        } else {
          hv = -__builtin_inff();
          hj = 1 << 30;
        }
      }
    }
  }
}

// ---------------- point-wise GEMM: Z = X@Wtop (z=0), Y = X@Wbot (z=1) ----------------
// grid (D/64, 256, 2)
__global__ __launch_bounds__(256) void feat_gemm(const float* __restrict__ A, int lda, int K,
                                                 const float* __restrict__ W, int D,
                                                 float* __restrict__ outT,
                                                 float* __restrict__ outB) {
  const float* Wz = W + (size_t)blockIdx.z * K * D;
  float* o = blockIdx.z ? outB : outT;
  int n0 = blockIdx.x * 64, m0 = blockIdx.y * 64;
  __shared__ float At[KC][68];
  __shared__ float Bt[KC][68];
  int t = threadIdx.x;
  int tx = t & 15, ty = t >> 4;
  float acc[4][4] = {};
  for (int k0 = 0; k0 < K; k0 += KC) {
    {
      int lk = t & 15, lr = t >> 4;
      int kk = k0 + lk;
      bool kv = kk < K;
#pragma unroll
      for (int u = 0; u < 4; ++u) {
        int r = lr + u * 16;
        At[lk][r] = kv ? A[(size_t)(m0 + r) * lda + kk] : 0.f;
      }
      int n = t & 63, kq0 = t >> 6;
#pragma unroll
      for (int u = 0; u < 4; ++u) {
        int kq = kq0 + u * 4;
        int kg = k0 + kq;
        Bt[kq][n] = (kg < K) ? Wz[(size_t)kg * D + n0 + n] : 0.f;
      }
    }
    __syncthreads();
#pragma unroll
    for (int q = 0; q < KC; ++q) {
      float4 a4 = *(const float4*)&At[q][ty * 4];
      float4 b4 = *(const float4*)&Bt[q][tx * 4];
      float a[4] = {a4.x, a4.y, a4.z, a4.w};
      float bv[4] = {b4.x, b4.y, b4.z, b4.w};
#pragma unroll
      for (int ii = 0; ii < 4; ++ii)
#pragma unroll
        for (int jj = 0; jj < 4; ++jj)
          acc[ii][jj] = fmaf(a[ii], bv[jj], acc[ii][jj]);
    }
    __syncthreads();
  }
#pragma unroll
  for (int ii = 0; ii < 4; ++ii) {
    float4 o4 = make_float4(acc[ii][0], acc[ii][1], acc[ii][2], acc[ii][3]);
    *(float4*)&o[(size_t)(m0 + ty * 4 + ii) * D + n0 + tx * 4] = o4;
  }
}

// ---------------- gather 16 neighbors, max, BN+ReLU, write into X5 slice ----------------
// grid BN_TOT, block D
__global__ __launch_bounds__(256) void gather_bn_relu(const float* __restrict__ ZT,
                                                      const float* __restrict__ YB,
                                                      const int* __restrict__ idx, int D,
                                                      const float* __restrict__ g,
                                                      const float* __restrict__ bta,
                                                      const float* __restrict__ mu,
                                                      const float* __restrict__ va,
                                                      float* __restrict__ X5, int coff) {
  __shared__ int nb[16];
  int bn = blockIdx.x, d = threadIdx.x;
  if (d < 16) nb[d] = idx[(size_t)bn * 16 + d];
  __syncthreads();
  float mx = -__builtin_inff();
#pragma unroll
  for (int j = 0; j < 16; ++j) mx = fmaxf(mx, YB[(size_t)nb[j] * D + d]);
  float h = ZT[(size_t)bn * D + d] + mx;
  float s = g[d] / sqrtf(va[d] + 1e-3f);
  float val = (h - mu[d]) * s + bta[d];
  X5[(size_t)bn * 512 + coff + d] = fmaxf(val, 0.f);
}

// ---------------- final 512x512 GEMM + BN + ReLU ----------------
// 128x128 tile, 8x8 micro, grid (4, 128)
__global__ __launch_bounds__(256) void final_gemm(const float* __restrict__ A,
                                                  const float* __restrict__ W,
                                                  const float* __restrict__ g,
                                                  const float* __restrict__ bta,
                                                  const float* __restrict__ mu,
                                                  const float* __restrict__ va,
                                                  float* __restrict__ out) {
  const int K = 512, D = 512;
  int n0 = blockIdx.x * 128, m0 = blockIdx.y * 128;
  __shared__ float At[KC][132];
  __shared__ float Bt[KC][132];
  int t = threadIdx.x;
  int tx = t & 15, ty = t >> 4;
  float acc[2][2][4][4] = {};
  for (int k0 = 0; k0 < K; k0 += KC) {
    {
      int lk = t & 15, lr = t >> 4;
      int kk = k0 + lk;
#pragma unroll
      for (int u = 0; u < 8; ++u) {
        int r = lr + u * 16;
        At[lk][r] = A[(size_t)(m0 + r) * 512 + kk];
      }
      int n = t & 127, kq0 = t >> 7;
#pragma unroll
      for (int u = 0; u < 8; ++u) {
        int kq = kq0 * 8 + u;
        Bt[kq][n] = W[(size_t)(k0 + kq) * D + n0 + n];
      }
    }
    __syncthreads();
#pragma unroll
    for (int q = 0; q < KC; ++q) {
      float4 a0 = *(const float4*)&At[q][ty * 4];
      float4 a1 = *(const float4*)&At[q][64 + ty * 4];
      float4 b0 = *(const float4*)&Bt[q][tx * 4];
      float4 b1 = *(const float4*)&Bt[q][64 + tx * 4];
      float a[2][4] = {{a0.x, a0.y, a0.z, a0.w}, {a1.x, a1.y, a1.z, a1.w}};
      float b[2][4] = {{b0.x, b0.y, b0.z, b0.w}, {b1.x, b1.y, b1.z, b1.w}};
#pragma unroll
      for (int hi = 0; hi < 2; ++hi)
#pragma unroll
        for (int hj = 0; hj < 2; ++hj)
#pragma unroll
          for (int ii = 0; ii < 4; ++ii)
#pragma unroll
            for (int jj = 0; jj < 4; ++jj)
              acc[hi][hj][ii][jj] = fmaf(a[hi][ii], b[hj][jj], acc[hi][hj][ii][jj]);
    }
    __syncthreads();
  }
  float sc[2][4], tc[2][4];
#pragma unroll
  for (int hj = 0; hj < 2; ++hj)
#pragma unroll
    for (int jj = 0; jj < 4; ++jj) {
      int col = n0 + hj * 64 + tx * 4 + jj;
      float s = g[col] / sqrtf(va[col] + 1e-3f);
      sc[hj][jj] = s;
      tc[hj][jj] = bta[col] - mu[col] * s;
    }
#pragma unroll
  for (int hi = 0; hi < 2; ++hi)
#pragma unroll
    for (int ii = 0; ii < 4; ++ii) {
      int m = m0 + hi * 64 + ty * 4 + ii;
#pragma unroll
      for (int hj = 0; hj < 2; ++hj) {
        float4 o4;
        o4.x = fmaxf(acc[hi][hj][ii][0] * sc[hj][0] + tc[hj][0], 0.f);
        o4.y = fmaxf(acc[hi][hj][ii][1] * sc[hj][1] + tc[hj][1], 0.f);
        o4.z = fmaxf(acc[hi][hj][ii][2] * sc[hj][2] + tc[hj][2], 0.f);
        o4.w = fmaxf(acc[hi][hj][ii][3] * sc[hj][3] + tc[hj][3], 0.f);
        *(float4*)&out[(size_t)m * 512 + n0 + hj * 64 + tx * 4] = o4;
      }
    }
}

extern "C" void kernel_launch(void* const* d_in, const int* in_sizes, int n_in,
                              void* d_out, int out_size, void* d_ws, size_t ws_size,
                              hipStream_t stream) {
  const float* x = (const float*)d_in[0];
  const float *W[5], *g[5], *bt[5], *mu[5], *va[5];
  for (int j = 0; j < 5; ++j) {
    W[j] = (const float*)d_in[1 + j * 5 + 0];
    g[j] = (const float*)d_in[1 + j * 5 + 1];
    bt[j] = (const float*)d_in[1 + j * 5 + 2];
    mu[j] = (const float*)d_in[1 + j * 5 + 3];
    va[j] = (const float*)d_in[1 + j * 5 + 4];
  }
  char* p = (char*)d_ws;
  float* X5 = (float*)p; p += (size_t)BN_TOT * 512 * 4;   // concat [x1|x2|x3|x4]
  float* ZT = (float*)p; p += (size_t)BN_TOT * 256 * 4;   // X @ Wtop
  float* YB = (float*)p; p += (size_t)BN_TOT * 256 * 4;   // X @ Wbot
  int* idx = (int*)p;    p += (size_t)BN_TOT * 16 * 4;    // global neighbor rows
  float* sq = (float*)p; p += (size_t)BN_TOT * 4;
  float* pd = (float*)p;
  size_t used = (size_t)(p - (char*)d_ws);
  size_t pdcap = (ws_size > used) ? (ws_size - used) / ((size_t)NP * NP * 4) : 0;
  int nb = (int)(pdcap < 1 ? 1 : (pdcap > (size_t)BTOT ? (size_t)BTOT : pdcap));

  struct Blk { const float* A; int lda, C, D, coff, w; };
  Blk blks[4] = {
      {x, 3, 3, 64, 0, 0},
      {X5 + 0, 512, 64, 64, 64, 1},
      {X5 + 64, 512, 64, 128, 128, 2},
      {X5 + 128, 512, 128, 256, 256, 3},
  };
  for (int q = 0; q < 4; ++q) {
    Blk& B = blks[q];
    sqnorm_kernel<<<BN_TOT / 4, 256, 0, stream>>>(B.A, B.lda, B.C, sq);
    for (int b0 = 0; b0 < BTOT; b0 += nb) {
      int cnt = (BTOT - b0 < nb) ? (BTOT - b0) : nb;
      dist_gemm<<<dim3(16, 16, cnt), 256, 0, stream>>>(B.A, B.lda, B.C, sq, pd, b0);
      topk_kernel<<<cnt * NP / 4, 256, 0, stream>>>(pd, idx, b0);
    }
    feat_gemm<<<dim3(B.D / 64, BN_TOT / 64, 2), 256, 0, stream>>>(
        B.A, B.lda, B.C, W[B.w], B.D, ZT, YB);
    gather_bn_relu<<<BN_TOT, B.D, 0, stream>>>(ZT, YB, idx, B.D, g[B.w], bt[B.w], mu[B.w],
                                               va[B.w], X5, B.coff);
  }
  final_gemm<<<dim3(512 / 128, BN_TOT / 128), 256, 0, stream>>>(X5, W[4], g[4], bt[4], mu[4],
                                                                va[4], (float*)d_out);
}

// Round 4
// 880.779 us; speedup vs baseline: 1.3930x; 1.0538x over previous
//
#include <hip/hip_runtime.h>

#define NP 2048
#define BTOT 8
#define BN_TOT 16384
#define KC 16
#define NTILE 32  // NP/64

// ---------------- squared norms: one wave per row ----------------
__global__ __launch_bounds__(256) void sqnorm_kernel(const float* __restrict__ X,
                                                     int lda, int C,
                                                     float* __restrict__ sq) {
  int wave = threadIdx.x >> 6, lane = threadIdx.x & 63;
  int row = blockIdx.x * 4 + wave;
  float s = 0.f;
  for (int c = lane; c < C; c += 64) {
    float t = X[(size_t)row * lda + c];
    s += t * t;
  }
#pragma unroll
  for (int off = 32; off > 0; off >>= 1) s += __shfl_xor(s, off, 64);
  if (lane == 0) sq[row] = s;
}

// ---------------- symmetric pairwise score GEMM ----------------
// Upper-triangular tile pairs (bi<=bj), 64x64 tile, 4x4 micro (R2-proven shape).
// Writes pd[i][j] = 2*dot - sq_j; for bi!=bj also pd[j][i] = 2*dot - sq_i.
// grid (528, 1, cnt_batches)
__global__ __launch_bounds__(256) void dist_gemm(const float* __restrict__ X, int lda, int K,
                                                 const float* __restrict__ sq,
                                                 float* __restrict__ pd, int batch0) {
  int bz = blockIdx.z;
  const float* Xb = X + (size_t)(batch0 + bz) * NP * lda;
  const float* sqb = sq + (size_t)(batch0 + bz) * NP;
  float* pdb = pd + (size_t)bz * NP * NP;
  // map linear pair index -> (bi, bj), bi <= bj
  int rem = blockIdx.x, bi = 0;
  while (rem >= NTILE - bi) { rem -= NTILE - bi; ++bi; }
  int bj = bi + rem;
  int i0 = bi * 64, j0 = bj * 64;
  __shared__ float At[KC][68];
  __shared__ float Bt[KC][68];
  int t = threadIdx.x;
  int tx = t & 15, ty = t >> 4;
  int lk = t & 15, lr = t >> 4;
  float acc[4][4] = {};
  for (int k0 = 0; k0 < K; k0 += KC) {
    int kk = k0 + lk;
    bool kv = kk < K;
#pragma unroll
    for (int u = 0; u < 4; ++u) {
      int r = lr + u * 16;
      At[lk][r] = kv ? Xb[(size_t)(i0 + r) * lda + kk] : 0.f;
      Bt[lk][r] = kv ? Xb[(size_t)(j0 + r) * lda + kk] : 0.f;
    }
    __syncthreads();
#pragma unroll
    for (int q = 0; q < KC; ++q) {
      float4 a4 = *(const float4*)&At[q][ty * 4];
      float4 b4 = *(const float4*)&Bt[q][tx * 4];
      float a[4] = {a4.x, a4.y, a4.z, a4.w};
      float bv[4] = {b4.x, b4.y, b4.z, b4.w};
#pragma unroll
      for (int ii = 0; ii < 4; ++ii)
#pragma unroll
        for (int jj = 0; jj < 4; ++jj)
          acc[ii][jj] = fmaf(a[ii], bv[jj], acc[ii][jj]);
    }
    __syncthreads();
  }
  float4 sqj4 = *(const float4*)&sqb[j0 + tx * 4];
#pragma unroll
  for (int ii = 0; ii < 4; ++ii) {
    int i = i0 + ty * 4 + ii;
    float4 o;
    o.x = 2.f * acc[ii][0] - sqj4.x;
    o.y = 2.f * acc[ii][1] - sqj4.y;
    o.z = 2.f * acc[ii][2] - sqj4.z;
    o.w = 2.f * acc[ii][3] - sqj4.w;
    *(float4*)&pdb[(size_t)i * NP + j0 + tx * 4] = o;
  }
  if (bi != bj) {
    float4 sqi4 = *(const float4*)&sqb[i0 + ty * 4];
#pragma unroll
    for (int jj = 0; jj < 4; ++jj) {
      int j = j0 + tx * 4 + jj;
      float4 o;
      o.x = 2.f * acc[0][jj] - sqi4.x;
      o.y = 2.f * acc[1][jj] - sqi4.y;
      o.z = 2.f * acc[2][jj] - sqi4.z;
      o.w = 2.f * acc[3][jj] - sqi4.w;
      *(float4*)&pdb[(size_t)j * NP + i0 + ty * 4] = o;
    }
  }
}

// ---------------- top-16 per row: threshold prefilter + wave select ----------------
__global__ __launch_bounds__(256) void topk_kernel(const float* __restrict__ pd,
                                                   int* __restrict__ idx_out, int batch0) {
  __shared__ float sv[4][1024];
  __shared__ int sj[4][1024];
  int wave = threadIdx.x >> 6, lane = threadIdx.x & 63;
  int row = blockIdx.x * 4 + wave;  // chunk-local row
  const float* prow = pd + (size_t)row * NP;
  int grow = batch0 * NP + row;
  int jb = (grow >> 11) << 11;
  int* out = idx_out + (size_t)grow * 16;

  float v[32];
#pragma unroll
  for (int t = 0; t < 32; ++t) v[t] = prow[lane + t * 64];
  float lmax = v[0];
#pragma unroll
  for (int t = 1; t < 32; ++t) lmax = fmaxf(lmax, v[t]);

  int rank = 0;
#pragma unroll
  for (int s = 0; s < 64; ++s) {
    float o = __shfl(lmax, s, 64);
    rank += (o > lmax) || (o == lmax && s < lane);
  }
  unsigned long long m15 = __ballot(rank == 15);
  float T0 = __shfl(lmax, (int)__builtin_ctzll(m15), 64);

  unsigned long long lowmask = (1ull << lane) - 1ull;
  int base = 0;
#pragma unroll
  for (int t = 0; t < 32; ++t) {
    bool keep = (v[t] >= T0);
    unsigned long long mk = __ballot(keep);
    if (keep) {
      int pos = base + (int)__popcll(mk & lowmask);
      if (pos < 1024) { sv[wave][pos] = v[t]; sj[wave][pos] = lane + t * 64; }
    }
    base += (int)__popcll(mk);
  }
  int cnt = base;

  if (cnt <= 1024) {
    __threadfence_block();
    for (int r = 0; r < 16; ++r) {
      float lbv = -__builtin_inff();
      int lbj = 1 << 30, lbp = -1;
      for (int i = lane; i < cnt; i += 64) {
        float cv = sv[wave][i];
        int cj = sj[wave][i];
        if (cv > lbv || (cv == lbv && cj < lbj)) { lbv = cv; lbj = cj; lbp = i; }
      }
      float bv = lbv;
      int bj = lbj;
#pragma unroll
      for (int off = 32; off > 0; off >>= 1) {
        float ov = __shfl_xor(bv, off, 64);
        int oj = __shfl_xor(bj, off, 64);
        if (ov > bv || (ov == bv && oj < bj)) { bv = ov; bj = oj; }
      }
      if (lane == 0) out[r] = jb + bj;
      if (lbp >= 0 && lbj == bj) sv[wave][lbp] = -__builtin_inff();
      __threadfence_block();
    }
    return;
  }

  {  // fallback (pathological ties)
    float vs[16];
    int js[16];
#pragma unroll
    for (int i = 0; i < 16; ++i) { vs[i] = -__builtin_inff(); js[i] = 1 << 30; }
    for (int t = 0; t < 32; ++t) {
      int j = lane + t * 64;
      float val = v[t];
      if (val > vs[15]) {
        vs[15] = val; js[15] = j;
#pragma unroll
        for (int p = 15; p > 0; --p) {
          if (vs[p] > vs[p - 1]) {
            float tv = vs[p]; vs[p] = vs[p - 1]; vs[p - 1] = tv;
            int tj = js[p]; js[p] = js[p - 1]; js[p - 1] = tj;
          }
        }
      }
    }
#pragma unroll
    for (int i = 0; i < 16; ++i) {
      sv[wave][lane * 16 + i] = vs[i];
      sj[wave][lane * 16 + i] = js[i];
    }
    int head = 0;
    float hv = sv[wave][lane * 16];
    int hj = sj[wave][lane * 16];
    for (int r = 0; r < 16; ++r) {
      float mv = hv;
      int mj = hj;
#pragma unroll
      for (int off = 32; off > 0; off >>= 1) {
        float ov = __shfl_xor(mv, off, 64);
        int oj = __shfl_xor(mj, off, 64);
        if (ov > mv || (ov == mv && oj < mj)) { mv = ov; mj = oj; }
      }
      if (lane == 0) out[r] = jb + mj;
      if (hj == mj) {
        ++head;
        if (head < 16) {
          hv = sv[wave][lane * 16 + head];
          hj = sj[wave][lane * 16 + head];
        } else {
          hv = -__builtin_inff();
          hj = 1 << 30;
        }
      }
    }
  }
}

// ---------------- layer-1 fused: C=3 scores from LDS + top-16 select ----------------
// One wave per row; whole batch (2048x3 floats, SoA) staged in LDS. grid BN_TOT/4.
__global__ __launch_bounds__(256) void dist3_topk(const float* __restrict__ x,
                                                  int* __restrict__ idx_out) {
  __shared__ float xs[3 * NP];
  __shared__ float sv[4][1024];
  __shared__ int sj[4][1024];
  int wave = threadIdx.x >> 6, lane = threadIdx.x & 63;
  int grow = blockIdx.x * 4 + wave;
  int b = grow >> 11;
  int row = grow & (NP - 1);
  const float* xb = x + (size_t)b * NP * 3;
  for (int t = threadIdx.x; t < 3 * NP; t += 256) {
    int n = t / 3, c = t - n * 3;
    xs[c * NP + n] = xb[t];  // SoA: conflict-free column reads later
  }
  __syncthreads();
  float xr0 = xs[row], xr1 = xs[NP + row], xr2 = xs[2 * NP + row];
  int jb = b << 11;
  int* out = idx_out + (size_t)grow * 16;

  float v[32];
#pragma unroll
  for (int t = 0; t < 32; ++t) {
    int j = lane + t * 64;
    float xj0 = xs[j], xj1 = xs[NP + j], xj2 = xs[2 * NP + j];
    float dot = xr0 * xj0 + xr1 * xj1 + xr2 * xj2;
    float sqj = xj0 * xj0 + xj1 * xj1 + xj2 * xj2;
    v[t] = 2.f * dot - sqj;
  }
  float lmax = v[0];
#pragma unroll
  for (int t = 1; t < 32; ++t) lmax = fmaxf(lmax, v[t]);

  int rank = 0;
#pragma unroll
  for (int s = 0; s < 64; ++s) {
    float o = __shfl(lmax, s, 64);
    rank += (o > lmax) || (o == lmax && s < lane);
  }
  unsigned long long m15 = __ballot(rank == 15);
  float T0 = __shfl(lmax, (int)__builtin_ctzll(m15), 64);

  unsigned long long lowmask = (1ull << lane) - 1ull;
  int base = 0;
#pragma unroll
  for (int t = 0; t < 32; ++t) {
    bool keep = (v[t] >= T0);
    unsigned long long mk = __ballot(keep);
    if (keep) {
      int pos = base + (int)__popcll(mk & lowmask);
      if (pos < 1024) { sv[wave][pos] = v[t]; sj[wave][pos] = lane + t * 64; }
    }
    base += (int)__popcll(mk);
  }
  int cnt = base;

  if (cnt <= 1024) {
    __threadfence_block();
    for (int r = 0; r < 16; ++r) {
      float lbv = -__builtin_inff();
      int lbj = 1 << 30, lbp = -1;
      for (int i = lane; i < cnt; i += 64) {
        float cv = sv[wave][i];
        int cj = sj[wave][i];
        if (cv > lbv || (cv == lbv && cj < lbj)) { lbv = cv; lbj = cj; lbp = i; }
      }
      float bv = lbv;
      int bj = lbj;
#pragma unroll
      for (int off = 32; off > 0; off >>= 1) {
        float ov = __shfl_xor(bv, off, 64);
        int oj = __shfl_xor(bj, off, 64);
        if (ov > bv || (ov == bv && oj < bj)) { bv = ov; bj = oj; }
      }
      if (lane == 0) out[r] = jb + bj;
      if (lbp >= 0 && lbj == bj) sv[wave][lbp] = -__builtin_inff();
      __threadfence_block();
    }
    return;
  }

  {  // fallback (pathological ties)
    float vs[16];
    int js[16];
#pragma unroll
    for (int i = 0; i < 16; ++i) { vs[i] = -__builtin_inff(); js[i] = 1 << 30; }
    for (int t = 0; t < 32; ++t) {
      int j = lane + t * 64;
      float val = v[t];
      if (val > vs[15]) {
        vs[15] = val; js[15] = j;
#pragma unroll
        for (int p = 15; p > 0; --p) {
          if (vs[p] > vs[p - 1]) {
            float tv = vs[p]; vs[p] = vs[p - 1]; vs[p - 1] = tv;
            int tj = js[p]; js[p] = js[p - 1]; js[p - 1] = tj;
          }
        }
      }
    }
#pragma unroll
    for (int i = 0; i < 16; ++i) {
      sv[wave][lane * 16 + i] = vs[i];
      sj[wave][lane * 16 + i] = js[i];
    }
    int head = 0;
    float hv = sv[wave][lane * 16];
    int hj = sj[wave][lane * 16];
    for (int r = 0; r < 16; ++r) {
      float mv = hv;
      int mj = hj;
#pragma unroll
      for (int off = 32; off > 0; off >>= 1) {
        float ov = __shfl_xor(mv, off, 64);
        int oj = __shfl_xor(mj, off, 64);
        if (ov > mv || (ov == mv && oj < mj)) { mv = ov; mj = oj; }
      }
      if (lane == 0) out[r] = jb + mj;
      if (hj == mj) {
        ++head;
        if (head < 16) {
          hv = sv[wave][lane * 16 + head];
          hj = sj[wave][lane * 16 + head];
        } else {
          hv = -__builtin_inff();
          hj = 1 << 30;
        }
      }
    }
  }
}

// ---------------- point-wise GEMM: Z = X@Wtop (z=0), Y = X@Wbot (z=1) ----------------
// grid (D/64, 256, 2)
__global__ __launch_bounds__(256) void feat_gemm(const float* __restrict__ A, int lda, int K,
                                                 const float* __restrict__ W, int D,
                                                 float* __restrict__ outT,
                                                 float* __restrict__ outB) {
  const float* Wz = W + (size_t)blockIdx.z * K * D;
  float* o = blockIdx.z ? outB : outT;
  int n0 = blockIdx.x * 64, m0 = blockIdx.y * 64;
  __shared__ float At[KC][68];
  __shared__ float Bt[KC][68];
  int t = threadIdx.x;
  int tx = t & 15, ty = t >> 4;
  float acc[4][4] = {};
  for (int k0 = 0; k0 < K; k0 += KC) {
    {
      int lk = t & 15, lr = t >> 4;
      int kk = k0 + lk;
      bool kv = kk < K;
#pragma unroll
      for (int u = 0; u < 4; ++u) {
        int r = lr + u * 16;
        At[lk][r] = kv ? A[(size_t)(m0 + r) * lda + kk] : 0.f;
      }
      int n = t & 63, kq0 = t >> 6;
#pragma unroll
      for (int u = 0; u < 4; ++u) {
        int kq = kq0 + u * 4;
        int kg = k0 + kq;
        Bt[kq][n] = (kg < K) ? Wz[(size_t)kg * D + n0 + n] : 0.f;
      }
    }
    __syncthreads();
#pragma unroll
    for (int q = 0; q < KC; ++q) {
      float4 a4 = *(const float4*)&At[q][ty * 4];
      float4 b4 = *(const float4*)&Bt[q][tx * 4];
      float a[4] = {a4.x, a4.y, a4.z, a4.w};
      float bv[4] = {b4.x, b4.y, b4.z, b4.w};
#pragma unroll
      for (int ii = 0; ii < 4; ++ii)
#pragma unroll
        for (int jj = 0; jj < 4; ++jj)
          acc[ii][jj] = fmaf(a[ii], bv[jj], acc[ii][jj]);
    }
    __syncthreads();
  }
#pragma unroll
  for (int ii = 0; ii < 4; ++ii) {
    float4 o4 = make_float4(acc[ii][0], acc[ii][1], acc[ii][2], acc[ii][3]);
    *(float4*)&o[(size_t)(m0 + ty * 4 + ii) * D + n0 + tx * 4] = o4;
  }
}

// ---------------- gather 16 neighbors, max, BN+ReLU, write into X5 slice ----------------
// grid BN_TOT, block D
__global__ __launch_bounds__(256) void gather_bn_relu(const float* __restrict__ ZT,
                                                      const float* __restrict__ YB,
                                                      const int* __restrict__ idx, int D,
                                                      const float* __restrict__ g,
                                                      const float* __restrict__ bta,
                                                      const float* __restrict__ mu,
                                                      const float* __restrict__ va,
                                                      float* __restrict__ X5, int coff) {
  __shared__ int nb[16];
  int bn = blockIdx.x, d = threadIdx.x;
  if (d < 16) nb[d] = idx[(size_t)bn * 16 + d];
  __syncthreads();
  float mx = -__builtin_inff();
#pragma unroll
  for (int j = 0; j < 16; ++j) mx = fmaxf(mx, YB[(size_t)nb[j] * D + d]);
  float h = ZT[(size_t)bn * D + d] + mx;
  float s = g[d] / sqrtf(va[d] + 1e-3f);
  float val = (h - mu[d]) * s + bta[d];
  X5[(size_t)bn * 512 + coff + d] = fmaxf(val, 0.f);
}

// ---------------- final 512x512 GEMM + BN + ReLU (R2-proven 64x64 shape) ----------------
// grid (8, 256)
__global__ __launch_bounds__(256) void final_gemm(const float* __restrict__ A,
                                                  const float* __restrict__ W,
                                                  const float* __restrict__ g,
                                                  const float* __restrict__ bta,
                                                  const float* __restrict__ mu,
                                                  const float* __restrict__ va,
                                                  float* __restrict__ out) {
  const int K = 512, D = 512;
  int n0 = blockIdx.x * 64, m0 = blockIdx.y * 64;
  __shared__ float At[KC][68];
  __shared__ float Bt[KC][68];
  int t = threadIdx.x;
  int tx = t & 15, ty = t >> 4;
  float acc[4][4] = {};
  for (int k0 = 0; k0 < K; k0 += KC) {
    {
      int lk = t & 15, lr = t >> 4;
      int kk = k0 + lk;
#pragma unroll
      for (int u = 0; u < 4; ++u) {
        int r = lr + u * 16;
        At[lk][r] = A[(size_t)(m0 + r) * 512 + kk];
      }
      int n = t & 63, kq0 = t >> 6;
#pragma unroll
      for (int u = 0; u < 4; ++u) {
        int kq = kq0 + u * 4;
        Bt[kq][n] = W[(size_t)(k0 + kq) * D + n0 + n];
      }
    }
    __syncthreads();
#pragma unroll
    for (int q = 0; q < KC; ++q) {
      float4 a4 = *(const float4*)&At[q][ty * 4];
      float4 b4 = *(const float4*)&Bt[q][tx * 4];
      float a[4] = {a4.x, a4.y, a4.z, a4.w};
      float bv[4] = {b4.x, b4.y, b4.z, b4.w};
#pragma unroll
      for (int ii = 0; ii < 4; ++ii)
#pragma unroll
        for (int jj = 0; jj < 4; ++jj)
          acc[ii][jj] = fmaf(a[ii], bv[jj], acc[ii][jj]);
    }
    __syncthreads();
  }
  float sc[4], tc[4];
#pragma unroll
  for (int jj = 0; jj < 4; ++jj) {
    int col = n0 + tx * 4 + jj;
    float s = g[col] / sqrtf(va[col] + 1e-3f);
    sc[jj] = s;
    tc[jj] = bta[col] - mu[col] * s;
  }
#pragma unroll
  for (int ii = 0; ii < 4; ++ii) {
    float4 o4;
    o4.x = fmaxf(acc[ii][0] * sc[0] + tc[0], 0.f);
    o4.y = fmaxf(acc[ii][1] * sc[1] + tc[1], 0.f);
    o4.z = fmaxf(acc[ii][2] * sc[2] + tc[2], 0.f);
    o4.w = fmaxf(acc[ii][3] * sc[3] + tc[3], 0.f);
    *(float4*)&out[(size_t)(m0 + ty * 4 + ii) * 512 + n0 + tx * 4] = o4;
  }
}

extern "C" void kernel_launch(void* const* d_in, const int* in_sizes, int n_in,
                              void* d_out, int out_size, void* d_ws, size_t ws_size,
                              hipStream_t stream) {
  const float* x = (const float*)d_in[0];
  const float *W[5], *g[5], *bt[5], *mu[5], *va[5];
  for (int j = 0; j < 5; ++j) {
    W[j] = (const float*)d_in[1 + j * 5 + 0];
    g[j] = (const float*)d_in[1 + j * 5 + 1];
    bt[j] = (const float*)d_in[1 + j * 5 + 2];
    mu[j] = (const float*)d_in[1 + j * 5 + 3];
    va[j] = (const float*)d_in[1 + j * 5 + 4];
  }
  char* p = (char*)d_ws;
  float* X5 = (float*)p; p += (size_t)BN_TOT * 512 * 4;   // concat [x1|x2|x3|x4]
  float* ZT = (float*)p; p += (size_t)BN_TOT * 256 * 4;   // X @ Wtop
  float* YB = (float*)p; p += (size_t)BN_TOT * 256 * 4;   // X @ Wbot
  int* idx = (int*)p;    p += (size_t)BN_TOT * 16 * 4;    // global neighbor rows
  float* sq = (float*)p; p += (size_t)BN_TOT * 4;
  float* pd = (float*)p;
  size_t used = (size_t)(p - (char*)d_ws);
  size_t pdcap = (ws_size > used) ? (ws_size - used) / ((size_t)NP * NP * 4) : 0;
  int nb = (int)(pdcap < 1 ? 1 : (pdcap > (size_t)BTOT ? (size_t)BTOT : pdcap));

  struct Blk { const float* A; int lda, C, D, coff, w; };
  Blk blks[4] = {
      {x, 3, 3, 64, 0, 0},
      {X5 + 0, 512, 64, 64, 64, 1},
      {X5 + 64, 512, 64, 128, 128, 2},
      {X5 + 128, 512, 128, 256, 256, 3},
  };
  for (int q = 0; q < 4; ++q) {
    Blk& B = blks[q];
    if (q == 0) {
      dist3_topk<<<BN_TOT / 4, 256, 0, stream>>>(x, idx);
    } else {
      sqnorm_kernel<<<BN_TOT / 4, 256, 0, stream>>>(B.A, B.lda, B.C, sq);
      for (int b0 = 0; b0 < BTOT; b0 += nb) {
        int cnt = (BTOT - b0 < nb) ? (BTOT - b0) : nb;
        dist_gemm<<<dim3(NTILE * (NTILE + 1) / 2, 1, cnt), 256, 0, stream>>>(
            B.A, B.lda, B.C, sq, pd, b0);
        topk_kernel<<<cnt * NP / 4, 256, 0, stream>>>(pd, idx, b0);
      }
    }
    feat_gemm<<<dim3(B.D / 64, BN_TOT / 64, 2), 256, 0, stream>>>(
        B.A, B.lda, B.C, W[B.w], B.D, ZT, YB);
    gather_bn_relu<<<BN_TOT, B.D, 0, stream>>>(ZT, YB, idx, B.D, g[B.w], bt[B.w], mu[B.w],
                                               va[B.w], X5, B.coff);
  }
  final_gemm<<<dim3(512 / 64, BN_TOT / 64), 256, 0, stream>>>(X5, W[4], g[4], bt[4], mu[4],
                                                              va[4], (float*)d_out);
}

// Round 5
// 684.741 us; speedup vs baseline: 1.7918x; 1.2863x over previous
//
#include <hip/hip_runtime.h>

#define NP 2048
#define BTOT 8
#define BN_TOT 16384
#define KC 16
#define NTILE 32  // NP/64
#define NEG_INF (-__builtin_inff())

// ---------------- shared top-16 selection (per-wave) ----------------
// v[32]: this lane's 32 candidate scores; jmap(t) -> global column index.
// svw/sjw: per-wave 256-slot LDS scratch. Writes the exact top-16 SET
// (ties at the 16th value -> smaller index, matching lax.top_k's set).
template <typename JM>
__device__ __forceinline__ void select16(const float (&v)[32], int lane, float* svw,
                                         int* sjw, int* out, int jb, JM jmap) {
  float lmax = v[0];
#pragma unroll
  for (int t = 1; t < 32; ++t) lmax = fmaxf(lmax, v[t]);

  // T0 = 16th-largest lane max (exact rank; (value,lane) is a strict order).
  int rank = 0;
  for (int s = 0; s < 64; ++s) {
    float o = __shfl(lmax, s, 64);
    rank += (o > lmax) || (o == lmax && s < lane);
  }
  unsigned long long m15 = __ballot(rank == 15);
  float T0 = __shfl(lmax, (int)__builtin_ctzll(m15), 64);
  // >=16 lanes have lmax >= T0 => cnt >= 16; every true top-16 value >= T0.

  // ballot-compact survivors into LDS (cap 256); remember own survivors.
  unsigned long long lowmask = (1ull << lane) - 1ull;
  unsigned keepmask = 0u;
  int base = 0;
#pragma unroll
  for (int t = 0; t < 32; ++t) {
    bool keep = (v[t] >= T0);
    unsigned long long mk = __ballot(keep);
    if (keep) {
      keepmask |= (1u << t);
      int pos = base + (int)__popcll(mk & lowmask);
      if (pos < 256) { svw[pos] = v[t]; sjw[pos] = jmap(t); }
    }
    base += (int)__popcll(mk);
  }
  int cnt = base;

  if (cnt <= 64) {
    // one-pass rank among survivors: no dependent shuffle chains.
    __threadfence_block();
    float mv = NEG_INF;
    int mj = 1 << 30;
    if (lane < cnt) { mv = svw[lane]; mj = sjw[lane]; }
    int rk = 0;
    for (int s = 0; s < 64; ++s) {
      float ov = __shfl(mv, s, 64);
      int oj = __shfl(mj, s, 64);
      rk += (ov > mv) || (ov == mv && oj < mj);
    }
    if (lane < cnt && rk < 16) out[rk] = jb + mj;  // ranks distinct (j distinct)
    return;
  }

  if (cnt <= 256) {
    // 16 rounds of wave argmax over LDS survivors.
    __threadfence_block();
    for (int r = 0; r < 16; ++r) {
      float lbv = NEG_INF;
      int lbj = 1 << 30, lbp = -1;
      for (int i = lane; i < cnt; i += 64) {
        float cv = svw[i];
        int cj = sjw[i];
        if (cv > lbv || (cv == lbv && cj < lbj)) { lbv = cv; lbj = cj; lbp = i; }
      }
      float bv = lbv;
      int bj = lbj;
#pragma unroll
      for (int off = 32; off > 0; off >>= 1) {
        float ov = __shfl_xor(bv, off, 64);
        int oj = __shfl_xor(bj, off, 64);
        if (ov > bv || (ov == bv && oj < bj)) { bv = ov; bj = oj; }
      }
      if (lane == 0) out[r] = jb + bj;
      if (lbp >= 0 && lbj == bj) svw[lbp] = NEG_INF;  // j unique -> one owner
      __threadfence_block();
    }
    return;
  }

  // register-mask fallback (pathological ties; LDS-free, any cnt).
  {
    unsigned avail = keepmask;  // top-16 is a subset of survivors
    for (int r = 0; r < 16; ++r) {
      float bv = NEG_INF;
      int bj = 1 << 30, bt = -1;
      unsigned am = avail;
      while (am) {
        int t = __builtin_ctz(am);
        am &= am - 1;
        float vv = v[t];
        int jj = jmap(t);
        if (vv > bv || (vv == bv && jj < bj)) { bv = vv; bj = jj; bt = t; }
      }
      float gv = bv;
      int gj = bj;
#pragma unroll
      for (int off = 32; off > 0; off >>= 1) {
        float ov = __shfl_xor(gv, off, 64);
        int oj = __shfl_xor(gj, off, 64);
        if (ov > gv || (ov == gv && oj < gj)) { gv = ov; gj = oj; }
      }
      if (lane == 0) out[r] = jb + gj;
      if (bt >= 0 && bj == gj) avail &= ~(1u << bt);
    }
  }
}

// ---------------- squared norms: one wave per row ----------------
__global__ __launch_bounds__(256) void sqnorm_kernel(const float* __restrict__ X,
                                                     int lda, int C,
                                                     float* __restrict__ sq) {
  int wave = threadIdx.x >> 6, lane = threadIdx.x & 63;
  int row = blockIdx.x * 4 + wave;
  float s = 0.f;
  for (int c = lane; c < C; c += 64) {
    float t = X[(size_t)row * lda + c];
    s += t * t;
  }
#pragma unroll
  for (int off = 32; off > 0; off >>= 1) s += __shfl_xor(s, off, 64);
  if (lane == 0) sq[row] = s;
}

// ---------------- symmetric pairwise score GEMM (R2-proven 64x64 shape) ----------------
// Upper-triangular tile pairs (bi<=bj); writes pd[i][j] = 2*dot - sq_j and,
// for bi!=bj, pd[j][i] = 2*dot - sq_i.  grid (528, 1, cnt_batches)
__global__ __launch_bounds__(256) void dist_gemm(const float* __restrict__ X, int lda, int K,
                                                 const float* __restrict__ sq,
                                                 float* __restrict__ pd, int batch0) {
  int bz = blockIdx.z;
  const float* Xb = X + (size_t)(batch0 + bz) * NP * lda;
  const float* sqb = sq + (size_t)(batch0 + bz) * NP;
  float* pdb = pd + (size_t)bz * NP * NP;
  int rem = blockIdx.x, bi = 0;
  while (rem >= NTILE - bi) { rem -= NTILE - bi; ++bi; }
  int bj = bi + rem;
  int i0 = bi * 64, j0 = bj * 64;
  __shared__ float At[KC][68];
  __shared__ float Bt[KC][68];
  int t = threadIdx.x;
  int tx = t & 15, ty = t >> 4;
  int lk = t & 15, lr = t >> 4;
  float acc[4][4] = {};
  for (int k0 = 0; k0 < K; k0 += KC) {
    int kk = k0 + lk;
    bool kv = kk < K;
#pragma unroll
    for (int u = 0; u < 4; ++u) {
      int r = lr + u * 16;
      At[lk][r] = kv ? Xb[(size_t)(i0 + r) * lda + kk] : 0.f;
      Bt[lk][r] = kv ? Xb[(size_t)(j0 + r) * lda + kk] : 0.f;
    }
    __syncthreads();
#pragma unroll
    for (int q = 0; q < KC; ++q) {
      float4 a4 = *(const float4*)&At[q][ty * 4];
      float4 b4 = *(const float4*)&Bt[q][tx * 4];
      float a[4] = {a4.x, a4.y, a4.z, a4.w};
      float bv[4] = {b4.x, b4.y, b4.z, b4.w};
#pragma unroll
      for (int ii = 0; ii < 4; ++ii)
#pragma unroll
        for (int jj = 0; jj < 4; ++jj)
          acc[ii][jj] = fmaf(a[ii], bv[jj], acc[ii][jj]);
    }
    __syncthreads();
  }
  float4 sqj4 = *(const float4*)&sqb[j0 + tx * 4];
#pragma unroll
  for (int ii = 0; ii < 4; ++ii) {
    int i = i0 + ty * 4 + ii;
    float4 o;
    o.x = 2.f * acc[ii][0] - sqj4.x;
    o.y = 2.f * acc[ii][1] - sqj4.y;
    o.z = 2.f * acc[ii][2] - sqj4.z;
    o.w = 2.f * acc[ii][3] - sqj4.w;
    *(float4*)&pdb[(size_t)i * NP + j0 + tx * 4] = o;
  }
  if (bi != bj) {
    float4 sqi4 = *(const float4*)&sqb[i0 + ty * 4];
#pragma unroll
    for (int jj = 0; jj < 4; ++jj) {
      int j = j0 + tx * 4 + jj;
      float4 o;
      o.x = 2.f * acc[0][jj] - sqi4.x;
      o.y = 2.f * acc[1][jj] - sqi4.y;
      o.z = 2.f * acc[2][jj] - sqi4.z;
      o.w = 2.f * acc[3][jj] - sqi4.w;
      *(float4*)&pdb[(size_t)j * NP + i0 + ty * 4] = o;
    }
  }
}

// ---------------- top-16 per row over materialized pd ----------------
// one wave per row, 4 waves/block; 8 KB LDS -> 8 blocks/CU.
__global__ __launch_bounds__(256) void topk_kernel(const float* __restrict__ pd,
                                                   int* __restrict__ idx_out, int batch0) {
  __shared__ float sv[4][256];
  __shared__ int sj[4][256];
  int wave = threadIdx.x >> 6, lane = threadIdx.x & 63;
  int row = blockIdx.x * 4 + wave;  // chunk-local row
  const float* prow = pd + (size_t)row * NP;
  int grow = batch0 * NP + row;
  int jb = (grow >> 11) << 11;
  float v[32];
#pragma unroll
  for (int u = 0; u < 8; ++u) {
    float4 q = *(const float4*)&prow[u * 256 + (lane << 2)];
    v[u * 4 + 0] = q.x;
    v[u * 4 + 1] = q.y;
    v[u * 4 + 2] = q.z;
    v[u * 4 + 3] = q.w;
  }
  select16(v, lane, sv[wave], sj[wave], idx_out + (size_t)grow * 16, jb,
           [lane](int t) { return ((t >> 2) << 8) + (lane << 2) + (t & 3); });
}

// ---------------- layer-1 fused: C=3 scores from LDS + top-16 ----------------
// 16 rows/block (4 waves x 4 rows), points staged as float4(x,y,z,sq).
// grid 1024 = exactly 4 blocks/CU x 256 CU.
__global__ __launch_bounds__(256) void dist3_topk(const float* __restrict__ x,
                                                  int* __restrict__ idx_out) {
  __shared__ float4 xs4[NP];    // 32 KB
  __shared__ float sv[4][256];  // 4 KB
  __shared__ int sj[4][256];    // 4 KB
  int wave = threadIdx.x >> 6, lane = threadIdx.x & 63;
  int b = blockIdx.x >> 7;             // 128 blocks per batch
  int row0 = (blockIdx.x & 127) * 16;  // 16 rows per block
  const float* xb = x + (size_t)b * NP * 3;
  for (int n = threadIdx.x; n < NP; n += 256) {
    float a0 = xb[3 * n], a1 = xb[3 * n + 1], a2 = xb[3 * n + 2];
    xs4[n] = make_float4(a0, a1, a2, a0 * a0 + a1 * a1 + a2 * a2);
  }
  __syncthreads();
  int jb = b << 11;
  for (int rr = 0; rr < 4; ++rr) {
    int row = row0 + wave * 4 + rr;
    float4 c = xs4[row];
    float v[32];
#pragma unroll
    for (int t = 0; t < 32; ++t) {
      int j = lane + t * 64;
      float4 p = xs4[j];
      float dot = c.x * p.x + c.y * p.y + c.z * p.z;
      v[t] = 2.f * dot - p.w;
    }
    select16(v, lane, sv[wave], sj[wave], idx_out + (size_t)(jb + row) * 16, jb,
             [lane](int t) { return lane + t * 64; });
  }
}

// ---------------- point-wise GEMM: Z = X@Wtop (z=0), Y = X@Wbot (z=1) ----------------
// grid (D/64, 256, 2)
__global__ __launch_bounds__(256) void feat_gemm(const float* __restrict__ A, int lda, int K,
                                                 const float* __restrict__ W, int D,
                                                 float* __restrict__ outT,
                                                 float* __restrict__ outB) {
  const float* Wz = W + (size_t)blockIdx.z * K * D;
  float* o = blockIdx.z ? outB : outT;
  int n0 = blockIdx.x * 64, m0 = blockIdx.y * 64;
  __shared__ float At[KC][68];
  __shared__ float Bt[KC][68];
  int t = threadIdx.x;
  int tx = t & 15, ty = t >> 4;
  float acc[4][4] = {};
  for (int k0 = 0; k0 < K; k0 += KC) {
    {
      int lk = t & 15, lr = t >> 4;
      int kk = k0 + lk;
      bool kv = kk < K;
#pragma unroll
      for (int u = 0; u < 4; ++u) {
        int r = lr + u * 16;
        At[lk][r] = kv ? A[(size_t)(m0 + r) * lda + kk] : 0.f;
      }
      int n = t & 63, kq0 = t >> 6;
#pragma unroll
      for (int u = 0; u < 4; ++u) {
        int kq = kq0 + u * 4;
        int kg = k0 + kq;
        Bt[kq][n] = (kg < K) ? Wz[(size_t)kg * D + n0 + n] : 0.f;
      }
    }
    __syncthreads();
#pragma unroll
    for (int q = 0; q < KC; ++q) {
      float4 a4 = *(const float4*)&At[q][ty * 4];
      float4 b4 = *(const float4*)&Bt[q][tx * 4];
      float a[4] = {a4.x, a4.y, a4.z, a4.w};
      float bv[4] = {b4.x, b4.y, b4.z, b4.w};
#pragma unroll
      for (int ii = 0; ii < 4; ++ii)
#pragma unroll
        for (int jj = 0; jj < 4; ++jj)
          acc[ii][jj] = fmaf(a[ii], bv[jj], acc[ii][jj]);
    }
    __syncthreads();
  }
#pragma unroll
  for (int ii = 0; ii < 4; ++ii) {
    float4 o4 = make_float4(acc[ii][0], acc[ii][1], acc[ii][2], acc[ii][3]);
    *(float4*)&o[(size_t)(m0 + ty * 4 + ii) * D + n0 + tx * 4] = o4;
  }
}

// ---------------- gather 16 neighbors, max, BN+ReLU, write into X5 slice ----------------
// grid BN_TOT, block D
__global__ __launch_bounds__(256) void gather_bn_relu(const float* __restrict__ ZT,
                                                      const float* __restrict__ YB,
                                                      const int* __restrict__ idx, int D,
                                                      const float* __restrict__ g,
                                                      const float* __restrict__ bta,
                                                      const float* __restrict__ mu,
                                                      const float* __restrict__ va,
                                                      float* __restrict__ X5, int coff) {
  __shared__ int nb[16];
  int bn = blockIdx.x, d = threadIdx.x;
  if (d < 16) nb[d] = idx[(size_t)bn * 16 + d];
  __syncthreads();
  float mx = NEG_INF;
#pragma unroll
  for (int j = 0; j < 16; ++j) mx = fmaxf(mx, YB[(size_t)nb[j] * D + d]);
  float h = ZT[(size_t)bn * D + d] + mx;
  float s = g[d] / sqrtf(va[d] + 1e-3f);
  float val = (h - mu[d]) * s + bta[d];
  X5[(size_t)bn * 512 + coff + d] = fmaxf(val, 0.f);
}

// ---------------- final 512x512 GEMM + BN + ReLU (R2-proven 64x64 shape) ----------------
// grid (8, 256)
__global__ __launch_bounds__(256) void final_gemm(const float* __restrict__ A,
                                                  const float* __restrict__ W,
                                                  const float* __restrict__ g,
                                                  const float* __restrict__ bta,
                                                  const float* __restrict__ mu,
                                                  const float* __restrict__ va,
                                                  float* __restrict__ out) {
  const int K = 512, D = 512;
  int n0 = blockIdx.x * 64, m0 = blockIdx.y * 64;
  __shared__ float At[KC][68];
  __shared__ float Bt[KC][68];
  int t = threadIdx.x;
  int tx = t & 15, ty = t >> 4;
  float acc[4][4] = {};
  for (int k0 = 0; k0 < K; k0 += KC) {
    {
      int lk = t & 15, lr = t >> 4;
      int kk = k0 + lk;
#pragma unroll
      for (int u = 0; u < 4; ++u) {
        int r = lr + u * 16;
        At[lk][r] = A[(size_t)(m0 + r) * 512 + kk];
      }
      int n = t & 63, kq0 = t >> 6;
#pragma unroll
      for (int u = 0; u < 4; ++u) {
        int kq = kq0 + u * 4;
        Bt[kq][n] = W[(size_t)(k0 + kq) * D + n0 + n];
      }
    }
    __syncthreads();
#pragma unroll
    for (int q = 0; q < KC; ++q) {
      float4 a4 = *(const float4*)&At[q][ty * 4];
      float4 b4 = *(const float4*)&Bt[q][tx * 4];
      float a[4] = {a4.x, a4.y, a4.z, a4.w};
      float bv[4] = {b4.x, b4.y, b4.z, b4.w};
#pragma unroll
      for (int ii = 0; ii < 4; ++ii)
#pragma unroll
        for (int jj = 0; jj < 4; ++jj)
          acc[ii][jj] = fmaf(a[ii], bv[jj], acc[ii][jj]);
    }
    __syncthreads();
  }
  float sc[4], tc[4];
#pragma unroll
  for (int jj = 0; jj < 4; ++jj) {
    int col = n0 + tx * 4 + jj;
    float s = g[col] / sqrtf(va[col] + 1e-3f);
    sc[jj] = s;
    tc[jj] = bta[col] - mu[col] * s;
  }
#pragma unroll
  for (int ii = 0; ii < 4; ++ii) {
    float4 o4;
    o4.x = fmaxf(acc[ii][0] * sc[0] + tc[0], 0.f);
    o4.y = fmaxf(acc[ii][1] * sc[1] + tc[1], 0.f);
    o4.z = fmaxf(acc[ii][2] * sc[2] + tc[2], 0.f);
    o4.w = fmaxf(acc[ii][3] * sc[3] + tc[3], 0.f);
    *(float4*)&out[(size_t)(m0 + ty * 4 + ii) * 512 + n0 + tx * 4] = o4;
  }
}

extern "C" void kernel_launch(void* const* d_in, const int* in_sizes, int n_in,
                              void* d_out, int out_size, void* d_ws, size_t ws_size,
                              hipStream_t stream) {
  const float* x = (const float*)d_in[0];
  const float *W[5], *g[5], *bt[5], *mu[5], *va[5];
  for (int j = 0; j < 5; ++j) {
    W[j] = (const float*)d_in[1 + j * 5 + 0];
    g[j] = (const float*)d_in[1 + j * 5 + 1];
    bt[j] = (const float*)d_in[1 + j * 5 + 2];
    mu[j] = (const float*)d_in[1 + j * 5 + 3];
    va[j] = (const float*)d_in[1 + j * 5 + 4];
  }
  char* p = (char*)d_ws;
  float* X5 = (float*)p; p += (size_t)BN_TOT * 512 * 4;   // concat [x1|x2|x3|x4]
  float* ZT = (float*)p; p += (size_t)BN_TOT * 256 * 4;   // X @ Wtop
  float* YB = (float*)p; p += (size_t)BN_TOT * 256 * 4;   // X @ Wbot
  int* idx = (int*)p;    p += (size_t)BN_TOT * 16 * 4;    // global neighbor rows
  float* sq = (float*)p; p += (size_t)BN_TOT * 4;
  float* pd = (float*)p;
  size_t used = (size_t)(p - (char*)d_ws);
  size_t pdcap = (ws_size > used) ? (ws_size - used) / ((size_t)NP * NP * 4) : 0;
  int nb = (int)(pdcap < 1 ? 1 : (pdcap > (size_t)BTOT ? (size_t)BTOT : pdcap));

  struct Blk { const float* A; int lda, C, D, coff, w; };
  Blk blks[4] = {
      {x, 3, 3, 64, 0, 0},
      {X5 + 0, 512, 64, 64, 64, 1},
      {X5 + 64, 512, 64, 128, 128, 2},
      {X5 + 128, 512, 128, 256, 256, 3},
  };
  for (int q = 0; q < 4; ++q) {
    Blk& B = blks[q];
    if (q == 0) {
      dist3_topk<<<1024, 256, 0, stream>>>(x, idx);
    } else {
      sqnorm_kernel<<<BN_TOT / 4, 256, 0, stream>>>(B.A, B.lda, B.C, sq);
      for (int b0 = 0; b0 < BTOT; b0 += nb) {
        int cnt = (BTOT - b0 < nb) ? (BTOT - b0) : nb;
        dist_gemm<<<dim3(NTILE * (NTILE + 1) / 2, 1, cnt), 256, 0, stream>>>(
            B.A, B.lda, B.C, sq, pd, b0);
        topk_kernel<<<cnt * NP / 4, 256, 0, stream>>>(pd, idx, b0);
      }
    }
    feat_gemm<<<dim3(B.D / 64, BN_TOT / 64, 2), 256, 0, stream>>>(
        B.A, B.lda, B.C, W[B.w], B.D, ZT, YB);
    gather_bn_relu<<<BN_TOT, B.D, 0, stream>>>(ZT, YB, idx, B.D, g[B.w], bt[B.w], mu[B.w],
                                               va[B.w], X5, B.coff);
  }
  final_gemm<<<dim3(512 / 64, BN_TOT / 64), 256, 0, stream>>>(X5, W[4], g[4], bt[4], mu[4],
                                                              va[4], (float*)d_out);
}

// Round 6
// 634.307 us; speedup vs baseline: 1.9342x; 1.0795x over previous
//
#include <hip/hip_runtime.h>

#define NP 2048
#define BTOT 8
#define BN_TOT 16384
#define KC 16
#define NTILE 32  // NP/64
#define NEG_INF (-__builtin_inff())

typedef __attribute__((ext_vector_type(8))) short short8;
typedef __attribute__((ext_vector_type(4))) float f32x4;

// ---------------- bf16 split helpers ----------------
__device__ __forceinline__ unsigned short bf16_rne(float x) {
  unsigned u = __float_as_uint(x);
  u += 0x7FFFu + ((u >> 16) & 1u);
  return (unsigned short)(u >> 16);
}
__device__ __forceinline__ void split2(float x, unsigned short& h, unsigned short& l) {
  h = bf16_rne(x);
  float hf = __uint_as_float((unsigned)h << 16);
  l = bf16_rne(x - hf);
}

// ---------------- shared top-16 selection (per-wave) ----------------
template <typename JM>
__device__ __forceinline__ void select16(const float (&v)[32], int lane, float* svw,
                                         int* sjw, int* out, int jb, JM jmap) {
  float lmax = v[0];
#pragma unroll
  for (int t = 1; t < 32; ++t) lmax = fmaxf(lmax, v[t]);
  int rank = 0;
  for (int s = 0; s < 64; ++s) {
    float o = __shfl(lmax, s, 64);
    rank += (o > lmax) || (o == lmax && s < lane);
  }
  unsigned long long m15 = __ballot(rank == 15);
  float T0 = __shfl(lmax, (int)__builtin_ctzll(m15), 64);

  unsigned long long lowmask = (1ull << lane) - 1ull;
  unsigned keepmask = 0u;
  int base = 0;
#pragma unroll
  for (int t = 0; t < 32; ++t) {
    bool keep = (v[t] >= T0);
    unsigned long long mk = __ballot(keep);
    if (keep) {
      keepmask |= (1u << t);
      int pos = base + (int)__popcll(mk & lowmask);
      if (pos < 256) { svw[pos] = v[t]; sjw[pos] = jmap(t); }
    }
    base += (int)__popcll(mk);
  }
  int cnt = base;

  if (cnt <= 64) {
    __threadfence_block();
    float mv = NEG_INF;
    int mj = 1 << 30;
    if (lane < cnt) { mv = svw[lane]; mj = sjw[lane]; }
    int rk = 0;
    for (int s = 0; s < 64; ++s) {
      float ov = __shfl(mv, s, 64);
      int oj = __shfl(mj, s, 64);
      rk += (ov > mv) || (ov == mv && oj < mj);
    }
    if (lane < cnt && rk < 16) out[rk] = jb + mj;
    return;
  }

  if (cnt <= 256) {
    __threadfence_block();
    for (int r = 0; r < 16; ++r) {
      float lbv = NEG_INF;
      int lbj = 1 << 30, lbp = -1;
      for (int i = lane; i < cnt; i += 64) {
        float cv = svw[i];
        int cj = sjw[i];
        if (cv > lbv || (cv == lbv && cj < lbj)) { lbv = cv; lbj = cj; lbp = i; }
      }
      float bv = lbv;
      int bj = lbj;
#pragma unroll
      for (int off = 32; off > 0; off >>= 1) {
        float ov = __shfl_xor(bv, off, 64);
        int oj = __shfl_xor(bj, off, 64);
        if (ov > bv || (ov == bv && oj < bj)) { bv = ov; bj = oj; }
      }
      if (lane == 0) out[r] = jb + bj;
      if (lbp >= 0 && lbj == bj) svw[lbp] = NEG_INF;
      __threadfence_block();
    }
    return;
  }

  {  // register-mask fallback (pathological ties)
    unsigned avail = keepmask;
    for (int r = 0; r < 16; ++r) {
      float bv = NEG_INF;
      int bj = 1 << 30, bt = -1;
      unsigned am = avail;
      while (am) {
        int t = __builtin_ctz(am);
        am &= am - 1;
        float vv = v[t];
        int jj = jmap(t);
        if (vv > bv || (vv == bv && jj < bj)) { bv = vv; bj = jj; bt = t; }
      }
      float gv = bv;
      int gj = bj;
#pragma unroll
      for (int off = 32; off > 0; off >>= 1) {
        float ov = __shfl_xor(gv, off, 64);
        int oj = __shfl_xor(gj, off, 64);
        if (ov > gv || (ov == gv && oj < gj)) { gv = ov; gj = oj; }
      }
      if (lane == 0) out[r] = jb + gj;
      if (bt >= 0 && bj == gj) avail &= ~(1u << bt);
    }
  }
}

// ---------------- squared norms: one wave per row ----------------
__global__ __launch_bounds__(256) void sqnorm_kernel(const float* __restrict__ X,
                                                     int lda, int C,
                                                     float* __restrict__ sq) {
  int wave = threadIdx.x >> 6, lane = threadIdx.x & 63;
  int row = blockIdx.x * 4 + wave;
  float s = 0.f;
  for (int c = lane; c < C; c += 64) {
    float t = X[(size_t)row * lda + c];
    s += t * t;
  }
#pragma unroll
  for (int off = 32; off > 0; off >>= 1) s += __shfl_xor(s, off, 64);
  if (lane == 0) sq[row] = s;
}

// ---------------- symmetric pairwise score GEMM (R2-proven 64x64 shape) ----------------
__global__ __launch_bounds__(256) void dist_gemm(const float* __restrict__ X, int lda, int K,
                                                 const float* __restrict__ sq,
                                                 float* __restrict__ pd, int batch0) {
  int bz = blockIdx.z;
  const float* Xb = X + (size_t)(batch0 + bz) * NP * lda;
  const float* sqb = sq + (size_t)(batch0 + bz) * NP;
  float* pdb = pd + (size_t)bz * NP * NP;
  int rem = blockIdx.x, bi = 0;
  while (rem >= NTILE - bi) { rem -= NTILE - bi; ++bi; }
  int bj = bi + rem;
  int i0 = bi * 64, j0 = bj * 64;
  __shared__ float At[KC][68];
  __shared__ float Bt[KC][68];
  int t = threadIdx.x;
  int tx = t & 15, ty = t >> 4;
  int lk = t & 15, lr = t >> 4;
  float acc[4][4] = {};
  for (int k0 = 0; k0 < K; k0 += KC) {
    int kk = k0 + lk;
    bool kv = kk < K;
#pragma unroll
    for (int u = 0; u < 4; ++u) {
      int r = lr + u * 16;
      At[lk][r] = kv ? Xb[(size_t)(i0 + r) * lda + kk] : 0.f;
      Bt[lk][r] = kv ? Xb[(size_t)(j0 + r) * lda + kk] : 0.f;
    }
    __syncthreads();
#pragma unroll
    for (int q = 0; q < KC; ++q) {
      float4 a4 = *(const float4*)&At[q][ty * 4];
      float4 b4 = *(const float4*)&Bt[q][tx * 4];
      float a[4] = {a4.x, a4.y, a4.z, a4.w};
      float bv[4] = {b4.x, b4.y, b4.z, b4.w};
#pragma unroll
      for (int ii = 0; ii < 4; ++ii)
#pragma unroll
        for (int jj = 0; jj < 4; ++jj)
          acc[ii][jj] = fmaf(a[ii], bv[jj], acc[ii][jj]);
    }
    __syncthreads();
  }
  float4 sqj4 = *(const float4*)&sqb[j0 + tx * 4];
#pragma unroll
  for (int ii = 0; ii < 4; ++ii) {
    int i = i0 + ty * 4 + ii;
    float4 o;
    o.x = 2.f * acc[ii][0] - sqj4.x;
    o.y = 2.f * acc[ii][1] - sqj4.y;
    o.z = 2.f * acc[ii][2] - sqj4.z;
    o.w = 2.f * acc[ii][3] - sqj4.w;
    *(float4*)&pdb[(size_t)i * NP + j0 + tx * 4] = o;
  }
  if (bi != bj) {
    float4 sqi4 = *(const float4*)&sqb[i0 + ty * 4];
#pragma unroll
    for (int jj = 0; jj < 4; ++jj) {
      int j = j0 + tx * 4 + jj;
      float4 o;
      o.x = 2.f * acc[0][jj] - sqi4.x;
      o.y = 2.f * acc[1][jj] - sqi4.y;
      o.z = 2.f * acc[2][jj] - sqi4.z;
      o.w = 2.f * acc[3][jj] - sqi4.w;
      *(float4*)&pdb[(size_t)j * NP + i0 + ty * 4] = o;
    }
  }
}

// ---------------- top-16 per row over materialized pd ----------------
__global__ __launch_bounds__(256) void topk_kernel(const float* __restrict__ pd,
                                                   int* __restrict__ idx_out, int batch0) {
  __shared__ float sv[4][256];
  __shared__ int sj[4][256];
  int wave = threadIdx.x >> 6, lane = threadIdx.x & 63;
  int row = blockIdx.x * 4 + wave;
  const float* prow = pd + (size_t)row * NP;
  int grow = batch0 * NP + row;
  int jb = (grow >> 11) << 11;
  float v[32];
#pragma unroll
  for (int u = 0; u < 8; ++u) {
    float4 q = *(const float4*)&prow[u * 256 + (lane << 2)];
    v[u * 4 + 0] = q.x;
    v[u * 4 + 1] = q.y;
    v[u * 4 + 2] = q.z;
    v[u * 4 + 3] = q.w;
  }
  select16(v, lane, sv[wave], sj[wave], idx_out + (size_t)grow * 16, jb,
           [lane](int t) { return ((t >> 2) << 8) + (lane << 2) + (t & 3); });
}

// ---------------- layer-1 fused: C=3 scores from LDS + top-16 ----------------
__global__ __launch_bounds__(256) void dist3_topk(const float* __restrict__ x,
                                                  int* __restrict__ idx_out) {
  __shared__ float4 xs4[NP];
  __shared__ float sv[4][256];
  __shared__ int sj[4][256];
  int wave = threadIdx.x >> 6, lane = threadIdx.x & 63;
  int b = blockIdx.x >> 7;
  int row0 = (blockIdx.x & 127) * 16;
  const float* xb = x + (size_t)b * NP * 3;
  for (int n = threadIdx.x; n < NP; n += 256) {
    float a0 = xb[3 * n], a1 = xb[3 * n + 1], a2 = xb[3 * n + 2];
    xs4[n] = make_float4(a0, a1, a2, a0 * a0 + a1 * a1 + a2 * a2);
  }
  __syncthreads();
  int jb = b << 11;
  for (int rr = 0; rr < 4; ++rr) {
    int row = row0 + wave * 4 + rr;
    float4 c = xs4[row];
    float v[32];
#pragma unroll
    for (int t = 0; t < 32; ++t) {
      int j = lane + t * 64;
      float4 p = xs4[j];
      float dot = c.x * p.x + c.y * p.y + c.z * p.z;
      v[t] = 2.f * dot - p.w;
    }
    select16(v, lane, sv[wave], sj[wave], idx_out + (size_t)(jb + row) * 16, jb,
             [lane](int t) { return lane + t * 64; });
  }
}

// ---------------- point-wise GEMM: Z = X@Wtop (z=0), Y = X@Wbot (z=1) ----------------
__global__ __launch_bounds__(256) void feat_gemm(const float* __restrict__ A, int lda, int K,
                                                 const float* __restrict__ W, int D,
                                                 float* __restrict__ outT,
                                                 float* __restrict__ outB) {
  const float* Wz = W + (size_t)blockIdx.z * K * D;
  float* o = blockIdx.z ? outB : outT;
  int n0 = blockIdx.x * 64, m0 = blockIdx.y * 64;
  __shared__ float At[KC][68];
  __shared__ float Bt[KC][68];
  int t = threadIdx.x;
  int tx = t & 15, ty = t >> 4;
  float acc[4][4] = {};
  for (int k0 = 0; k0 < K; k0 += KC) {
    {
      int lk = t & 15, lr = t >> 4;
      int kk = k0 + lk;
      bool kv = kk < K;
#pragma unroll
      for (int u = 0; u < 4; ++u) {
        int r = lr + u * 16;
        At[lk][r] = kv ? A[(size_t)(m0 + r) * lda + kk] : 0.f;
      }
      int n = t & 63, kq0 = t >> 6;
#pragma unroll
      for (int u = 0; u < 4; ++u) {
        int kq = kq0 + u * 4;
        int kg = k0 + kq;
        Bt[kq][n] = (kg < K) ? Wz[(size_t)kg * D + n0 + n] : 0.f;
      }
    }
    __syncthreads();
#pragma unroll
    for (int q = 0; q < KC; ++q) {
      float4 a4 = *(const float4*)&At[q][ty * 4];
      float4 b4 = *(const float4*)&Bt[q][tx * 4];
      float a[4] = {a4.x, a4.y, a4.z, a4.w};
      float bv[4] = {b4.x, b4.y, b4.z, b4.w};
#pragma unroll
      for (int ii = 0; ii < 4; ++ii)
#pragma unroll
        for (int jj = 0; jj < 4; ++jj)
          acc[ii][jj] = fmaf(a[ii], bv[jj], acc[ii][jj]);
    }
    __syncthreads();
  }
#pragma unroll
  for (int ii = 0; ii < 4; ++ii) {
    float4 o4 = make_float4(acc[ii][0], acc[ii][1], acc[ii][2], acc[ii][3]);
    *(float4*)&o[(size_t)(m0 + ty * 4 + ii) * D + n0 + tx * 4] = o4;
  }
}

// ---------------- gather 16 neighbors, max, BN+ReLU, write into X5 slice ----------------
__global__ __launch_bounds__(256) void gather_bn_relu(const float* __restrict__ ZT,
                                                      const float* __restrict__ YB,
                                                      const int* __restrict__ idx, int D,
                                                      const float* __restrict__ g,
                                                      const float* __restrict__ bta,
                                                      const float* __restrict__ mu,
                                                      const float* __restrict__ va,
                                                      float* __restrict__ X5, int coff) {
  __shared__ int nb[16];
  int bn = blockIdx.x, d = threadIdx.x;
  if (d < 16) nb[d] = idx[(size_t)bn * 16 + d];
  __syncthreads();
  float mx = NEG_INF;
#pragma unroll
  for (int j = 0; j < 16; ++j) mx = fmaxf(mx, YB[(size_t)nb[j] * D + d]);
  float h = ZT[(size_t)bn * D + d] + mx;
  float s = g[d] / sqrtf(va[d] + 1e-3f);
  float val = (h - mu[d]) * s + bta[d];
  X5[(size_t)bn * 512 + coff + d] = fmaxf(val, 0.f);
}

// ---------------- split X5 (f32) -> hi/lo bf16, grid-stride float4 ----------------
__global__ __launch_bounds__(256) void split_x5(const float* __restrict__ X5,
                                                unsigned short* __restrict__ Xh,
                                                unsigned short* __restrict__ Xl) {
  const int total4 = BN_TOT * 512 / 4;
  for (int i = blockIdx.x * 256 + threadIdx.x; i < total4; i += gridDim.x * 256) {
    float4 v = *(const float4*)&X5[i * 4];
    ushort4 h, l;
    split2(v.x, h.x, l.x);
    split2(v.y, h.y, l.y);
    split2(v.z, h.z, l.z);
    split2(v.w, h.w, l.w);
    *(ushort4*)&Xh[i * 4] = h;
    *(ushort4*)&Xl[i * 4] = l;
  }
}

// ---------------- W5^T split: Wt[n][k] = split(W5[k][n]) ----------------
// grid 512 (one block per output row n), coalesced writes.
__global__ __launch_bounds__(256) void w5t_split(const float* __restrict__ W5,
                                                 unsigned short* __restrict__ Wh,
                                                 unsigned short* __restrict__ Wl) {
  int n = blockIdx.x;
  for (int k = threadIdx.x; k < 512; k += 256) {
    unsigned short h, l;
    split2(W5[(size_t)k * 512 + n], h, l);
    Wh[(size_t)n * 512 + k] = h;
    Wl[(size_t)n * 512 + k] = l;
  }
}

// ---------------- final GEMM via split-bf16 MFMA, no LDS ----------------
// out = relu(bn(X5 @ W5)).  A-frags from Xh/Xl rows (contiguous), B-frags from
// W5T rows (contiguous).  Wave tile 64x64 = 4x4 mfma_f32_16x16x32_bf16 tiles,
// 3 passes (hh, hl, lh).  Block = 2x2 waves = 128x128.  grid (4, 128).
__global__ __launch_bounds__(256) void final_mfma(const unsigned short* __restrict__ Ah,
                                                  const unsigned short* __restrict__ Al,
                                                  const unsigned short* __restrict__ Bh,
                                                  const unsigned short* __restrict__ Bl,
                                                  const float* __restrict__ g,
                                                  const float* __restrict__ bta,
                                                  const float* __restrict__ mu,
                                                  const float* __restrict__ va,
                                                  float* __restrict__ out) {
  int tid = threadIdx.x;
  int wave = tid >> 6, lane = tid & 63;
  int wm = wave >> 1, wn = wave & 1;
  int ln = lane & 15, quad = lane >> 4;
  int m_base = blockIdx.y * 128 + wm * 64;
  int n_base = blockIdx.x * 128 + wn * 64;

  f32x4 acc[4][4];
#pragma unroll
  for (int i = 0; i < 4; ++i)
#pragma unroll
    for (int j = 0; j < 4; ++j) acc[i][j] = (f32x4){0.f, 0.f, 0.f, 0.f};

  // per-lane base offsets (element index); frag k-offset = kk*32 + quad*8
  size_t aoff[4], boff[4];
#pragma unroll
  for (int t = 0; t < 4; ++t) {
    aoff[t] = (size_t)(m_base + t * 16 + ln) * 512 + quad * 8;
    boff[t] = (size_t)(n_base + t * 16 + ln) * 512 + quad * 8;
  }

  short8 cAh[4], cAl[4], cBh[4], cBl[4];
#pragma unroll
  for (int t = 0; t < 4; ++t) {
    cAh[t] = *(const short8*)(Ah + aoff[t]);
    cAl[t] = *(const short8*)(Al + aoff[t]);
    cBh[t] = *(const short8*)(Bh + boff[t]);
    cBl[t] = *(const short8*)(Bl + boff[t]);
  }

  for (int kk = 0; kk < 16; ++kk) {
    short8 nAh[4], nAl[4], nBh[4], nBl[4];
    if (kk < 15) {
      int ko = (kk + 1) * 32;
#pragma unroll
      for (int t = 0; t < 4; ++t) {
        nAh[t] = *(const short8*)(Ah + aoff[t] + ko);
        nAl[t] = *(const short8*)(Al + aoff[t] + ko);
        nBh[t] = *(const short8*)(Bh + boff[t] + ko);
        nBl[t] = *(const short8*)(Bl + boff[t] + ko);
      }
    }
#pragma unroll
    for (int tm = 0; tm < 4; ++tm)
#pragma unroll
      for (int tn = 0; tn < 4; ++tn) {
        acc[tm][tn] = __builtin_amdgcn_mfma_f32_16x16x32_bf16(cAh[tm], cBh[tn],
                                                              acc[tm][tn], 0, 0, 0);
        acc[tm][tn] = __builtin_amdgcn_mfma_f32_16x16x32_bf16(cAh[tm], cBl[tn],
                                                              acc[tm][tn], 0, 0, 0);
        acc[tm][tn] = __builtin_amdgcn_mfma_f32_16x16x32_bf16(cAl[tm], cBh[tn],
                                                              acc[tm][tn], 0, 0, 0);
      }
    if (kk < 15) {
#pragma unroll
      for (int t = 0; t < 4; ++t) {
        cAh[t] = nAh[t];
        cAl[t] = nAl[t];
        cBh[t] = nBh[t];
        cBl[t] = nBl[t];
      }
    }
  }

  // epilogue: C/D layout col=lane&15, row=quad*4+reg (m89-verified)
#pragma unroll
  for (int tn = 0; tn < 4; ++tn) {
    int col = n_base + tn * 16 + ln;
    float s = g[col] / sqrtf(va[col] + 1e-3f);
    float tc = bta[col] - mu[col] * s;
#pragma unroll
    for (int tm = 0; tm < 4; ++tm) {
      int mrow = m_base + tm * 16 + quad * 4;
#pragma unroll
      for (int r = 0; r < 4; ++r) {
        float val = acc[tm][tn][r] * s + tc;
        out[(size_t)(mrow + r) * 512 + col] = fmaxf(val, 0.f);
      }
    }
  }
}

extern "C" void kernel_launch(void* const* d_in, const int* in_sizes, int n_in,
                              void* d_out, int out_size, void* d_ws, size_t ws_size,
                              hipStream_t stream) {
  const float* x = (const float*)d_in[0];
  const float *W[5], *g[5], *bt[5], *mu[5], *va[5];
  for (int j = 0; j < 5; ++j) {
    W[j] = (const float*)d_in[1 + j * 5 + 0];
    g[j] = (const float*)d_in[1 + j * 5 + 1];
    bt[j] = (const float*)d_in[1 + j * 5 + 2];
    mu[j] = (const float*)d_in[1 + j * 5 + 3];
    va[j] = (const float*)d_in[1 + j * 5 + 4];
  }
  char* p = (char*)d_ws;
  float* X5 = (float*)p; p += (size_t)BN_TOT * 512 * 4;   // concat [x1|x2|x3|x4]
  float* ZT = (float*)p; p += (size_t)BN_TOT * 256 * 4;   // X @ Wtop
  float* YB = (float*)p; p += (size_t)BN_TOT * 256 * 4;   // X @ Wbot
  int* idx = (int*)p;    p += (size_t)BN_TOT * 16 * 4;    // global neighbor rows
  float* sq = (float*)p; p += (size_t)BN_TOT * 4;
  unsigned short* X5h = (unsigned short*)p; p += (size_t)BN_TOT * 512 * 2;
  unsigned short* X5l = (unsigned short*)p; p += (size_t)BN_TOT * 512 * 2;
  unsigned short* W5h = (unsigned short*)p; p += (size_t)512 * 512 * 2;
  unsigned short* W5l = (unsigned short*)p; p += (size_t)512 * 512 * 2;
  float* pd = (float*)p;
  size_t used = (size_t)(p - (char*)d_ws);
  size_t pdcap = (ws_size > used) ? (ws_size - used) / ((size_t)NP * NP * 4) : 0;
  int nb = (int)(pdcap < 1 ? 1 : (pdcap > (size_t)BTOT ? (size_t)BTOT : pdcap));

  w5t_split<<<512, 256, 0, stream>>>(W[4], W5h, W5l);

  struct Blk { const float* A; int lda, C, D, coff, w; };
  Blk blks[4] = {
      {x, 3, 3, 64, 0, 0},
      {X5 + 0, 512, 64, 64, 64, 1},
      {X5 + 64, 512, 64, 128, 128, 2},
      {X5 + 128, 512, 128, 256, 256, 3},
  };
  for (int q = 0; q < 4; ++q) {
    Blk& B = blks[q];
    if (q == 0) {
      dist3_topk<<<1024, 256, 0, stream>>>(x, idx);
    } else {
      sqnorm_kernel<<<BN_TOT / 4, 256, 0, stream>>>(B.A, B.lda, B.C, sq);
      for (int b0 = 0; b0 < BTOT; b0 += nb) {
        int cnt = (BTOT - b0 < nb) ? (BTOT - b0) : nb;
        dist_gemm<<<dim3(NTILE * (NTILE + 1) / 2, 1, cnt), 256, 0, stream>>>(
            B.A, B.lda, B.C, sq, pd, b0);
        topk_kernel<<<cnt * NP / 4, 256, 0, stream>>>(pd, idx, b0);
      }
    }
    feat_gemm<<<dim3(B.D / 64, BN_TOT / 64, 2), 256, 0, stream>>>(
        B.A, B.lda, B.C, W[B.w], B.D, ZT, YB);
    gather_bn_relu<<<BN_TOT, B.D, 0, stream>>>(ZT, YB, idx, B.D, g[B.w], bt[B.w], mu[B.w],
                                               va[B.w], X5, B.coff);
  }
  split_x5<<<1024, 256, 0, stream>>>(X5, X5h, X5l);
  final_mfma<<<dim3(4, 128), 256, 0, stream>>>(X5h, X5l, W5h, W5l, g[4], bt[4], mu[4],
                                               va[4], (float*)d_out);
}